// Round 5
// baseline (280.047 us; speedup 1.0000x reference)
//
#include <hip/hip_runtime.h>
#include <math.h>

#define TT 8192
#define DD 128
#define GB 64
#define GN 128
#define GE 2048
#define NEDGE (GB*GE)   // 131072

// ---- workspace layout (bytes) ----
#define WS_COUNT   0u            // 8192 int
#define WS_FILL    (32u<<10)     // 8192 int
#define WS_OFFS    (64u<<10)     // 8193 int
#define WS_NORM    (100u<<10)    // 8192 f32
#define WS_CSR     (132u<<10)    // 131072 int
#define WS_W2      (644u<<10)    // 128*128 f32
#define WS_B2      (708u<<10)    // 128 f32
#define WS_PM      (709u<<10)    // 4*8192 f32 (128K)
#define WS_PL      (837u<<10)    // 4*8192 f32 (128K)  (ends 965K < 1M)
#define WS_H0      (1u<<20)      // 4MB region: GCN h0; later q16 (2MB)
#define WS_H1      (5u<<20)      // 4MB region: GCN h1; later k16 frag-order (2MB)
#define WS_M       (9u<<20)      // 4MB region: GCN mbuf; later vT frag-order (2MB)
#define WS_OPART   (13u<<20)     // 8MB: 4 x 8192 x 128 f16 partials
// total 21MB

typedef _Float16 hfrag  __attribute__((ext_vector_type(8)));
typedef _Float16 h4     __attribute__((ext_vector_type(4)));
typedef float    ffrag  __attribute__((ext_vector_type(4)));

#define MFMA16(a,b,c) __builtin_amdgcn_mfma_f32_16x16x32_f16((a),(b),(c),0,0,0)

typedef __attribute__((address_space(1))) unsigned int gu32_t;
typedef __attribute__((address_space(3))) unsigned int lu32_t;
#define GLOAD16(gp, lp) __builtin_amdgcn_global_load_lds((gu32_t*)(const void*)(gp), (lu32_t*)(void*)(lp), 16, 0, 0)

__global__ __launch_bounds__(256) void k_count(const int* __restrict__ edges, int* __restrict__ count) {
  int e = blockIdx.x*256 + threadIdx.x;
  int b = e >> 11;
  int i = e & 2047;
  int dst = edges[b*2*GE + GE + i] + b*GN;
  atomicAdd(&count[dst], 1);
}

__global__ __launch_bounds__(1024) void k_scan(const int* __restrict__ count, int* __restrict__ offs,
                                               float* __restrict__ norm) {
  __shared__ int lds[1024];
  int tid = threadIdx.x;
  int base = tid*8;
  int loc[8]; int tot = 0;
  #pragma unroll
  for (int j=0;j<8;j++){ loc[j]=count[base+j]; tot+=loc[j]; }
  lds[tid]=tot; __syncthreads();
  for (int s=1;s<1024;s<<=1){
    int v = (tid>=s)? lds[tid-s] : 0;
    __syncthreads();
    lds[tid]+=v;
    __syncthreads();
  }
  int ex = lds[tid]-tot;
  #pragma unroll
  for (int j=0;j<8;j++){
    offs[base+j]=ex; ex+=loc[j];
    norm[base+j]=rsqrtf(1.0f+(float)loc[j]);
  }
  if (tid==1023) offs[TT]=ex;
}

__global__ __launch_bounds__(256) void k_fill(const int* __restrict__ edges, const int* __restrict__ offs,
                                              int* __restrict__ fill, int* __restrict__ csr) {
  int e = blockIdx.x*256+threadIdx.x;
  int b = e>>11, i = e&2047;
  int s = edges[b*2*GE + i] + b*GN;
  int d = edges[b*2*GE + GE + i] + b*GN;
  int pos = offs[d] + atomicAdd(&fill[d],1);
  csr[pos] = s;
}

// C[M,128] = A[M,128] @ W[128,128] (+bias), written at C[row*ldc + cofs + col]
__global__ __launch_bounds__(256) void k_gemm(const float* __restrict__ A, const float* __restrict__ W,
                                              const float* __restrict__ bias, float* __restrict__ C,
                                              int ldc, int cofs) {
  __shared__ float As[32*132];
  __shared__ float Ws[128*132];
  int tid = threadIdx.x;
  int row0 = blockIdx.x*32;
  #pragma unroll
  for (int i=0;i<4;i++){
    int idx = i*256+tid;
    int r = idx>>5, c4 = (idx&31)<<2;
    *(float4*)&As[r*132+c4] = *(const float4*)&A[(row0+r)*DD + c4];
  }
  #pragma unroll
  for (int i=0;i<16;i++){
    int idx = i*256+tid;
    int r = idx>>5, c4 = (idx&31)<<2;
    *(float4*)&Ws[r*132+c4] = *(const float4*)&W[r*DD + c4];
  }
  __syncthreads();
  int rg = tid>>4, cg = tid&15;
  int r0 = rg*2, c0 = cg*8;
  float acc[2][8];
  #pragma unroll
  for (int a=0;a<2;a++)
    #pragma unroll
    for (int b=0;b<8;b++) acc[a][b]=0.f;
  for (int kk=0;kk<128;kk+=4){
    float a0[4], a1[4];
    *(float4*)a0 = *(float4*)&As[r0*132+kk];
    *(float4*)a1 = *(float4*)&As[(r0+1)*132+kk];
    #pragma unroll
    for (int j=0;j<4;j++){
      float w[8];
      *(float4*)&w[0] = *(float4*)&Ws[(kk+j)*132+c0];
      *(float4*)&w[4] = *(float4*)&Ws[(kk+j)*132+c0+4];
      #pragma unroll
      for (int m=0;m<8;m++){
        acc[0][m] += a0[j]*w[m];
        acc[1][m] += a1[j]*w[m];
      }
    }
  }
  #pragma unroll
  for (int a=0;a<2;a++){
    float outv[8];
    #pragma unroll
    for (int m=0;m<8;m++)
      outv[m] = acc[a][m] + (bias ? bias[c0+m] : 0.f);
    float* dst = &C[(size_t)(row0+r0+a)*ldc + cofs + c0];
    *(float4*)&dst[0] = *(float4*)&outv[0];
    *(float4*)&dst[4] = *(float4*)&outv[4];
  }
}

// merged Q/K/V projections -> f16, one launch, grid 768.
// mode 0 (Q): q16[row][d]                              (plain)
// mode 1 (K): fragment-order: frag (R=row/16, ds=d/32): elem ((R*4+ds)*64 + (row&15) + 16*g)*8 + j
// mode 2 (V): V^T fragment-order with PV k-permutation kappa(g,j)=16*(j>>2)+4g+(j&3):
//             elem ((C*8 + nt)*64 + (d&15) + 16*gx)*8 + jx, C=row/32, nt=d/16,
//             gx=(kloc&15)>>2, jx=((kloc>>4)<<2)|(kloc&3), kloc=row&31
__global__ __launch_bounds__(256) void k_proj3(const float* __restrict__ A,
                                               const float* __restrict__ Wq, const float* __restrict__ bq_,
                                               const float* __restrict__ Wk, const float* __restrict__ bk_,
                                               const float* __restrict__ Wv, const float* __restrict__ bv_,
                                               _Float16* __restrict__ q16,
                                               _Float16* __restrict__ k16,
                                               _Float16* __restrict__ vT) {
  __shared__ float As[32*132];
  __shared__ float Ws[128*132];
  const int mode = blockIdx.x >> 8;
  const int row0 = (blockIdx.x & 255) * 32;
  const float* W    = (mode==0) ? Wq : (mode==1) ? Wk : Wv;
  const float* bias = (mode==0) ? bq_ : (mode==1) ? bk_ : bv_;
  int tid = threadIdx.x;
  #pragma unroll
  for (int i=0;i<4;i++){
    int idx = i*256+tid;
    int r = idx>>5, c4 = (idx&31)<<2;
    *(float4*)&As[r*132+c4] = *(const float4*)&A[(row0+r)*DD + c4];
  }
  #pragma unroll
  for (int i=0;i<16;i++){
    int idx = i*256+tid;
    int r = idx>>5, c4 = (idx&31)<<2;
    *(float4*)&Ws[r*132+c4] = *(const float4*)&W[r*DD + c4];
  }
  __syncthreads();
  int rg = tid>>4, cg = tid&15;
  int r0 = rg*2, c0 = cg*8;
  float acc[2][8];
  #pragma unroll
  for (int a=0;a<2;a++)
    #pragma unroll
    for (int b=0;b<8;b++) acc[a][b]=0.f;
  for (int kk=0;kk<128;kk+=4){
    float a0[4], a1[4];
    *(float4*)a0 = *(float4*)&As[r0*132+kk];
    *(float4*)a1 = *(float4*)&As[(r0+1)*132+kk];
    #pragma unroll
    for (int j=0;j<4;j++){
      float w[8];
      *(float4*)&w[0] = *(float4*)&Ws[(kk+j)*132+c0];
      *(float4*)&w[4] = *(float4*)&Ws[(kk+j)*132+c0+4];
      #pragma unroll
      for (int m=0;m<8;m++){
        acc[0][m] += a0[j]*w[m];
        acc[1][m] += a1[j]*w[m];
      }
    }
  }
  #pragma unroll
  for (int a=0;a<2;a++){
    int row = row0 + r0 + a;
    float val[8];
    #pragma unroll
    for (int m=0;m<8;m++) val[m] = acc[a][m] + bias[c0+m];
    if (mode == 0) {
      hfrag t;
      #pragma unroll
      for (int m=0;m<8;m++) t[m] = (_Float16)val[m];
      *(hfrag*)&q16[(size_t)row*DD + c0] = t;
    } else if (mode == 1) {
      hfrag t;
      #pragma unroll
      for (int m=0;m<8;m++) t[m] = (_Float16)val[m];
      int R = row>>4, l15r = row&15, dsx = cg>>2, gx = cg&3;
      *(hfrag*)&k16[((size_t)(R*4+dsx)*64 + l15r + 16*gx)*8] = t;
    } else {
      int C = row>>5, kloc = row&31;
      int gx = (kloc&15)>>2;
      int jx = ((kloc>>4)<<2) | (kloc&3);
      #pragma unroll
      for (int m=0;m<8;m++){
        int d = c0+m;
        vT[((size_t)(C*8 + (d>>4))*64 + (d&15) + 16*gx)*8 + jx] = (_Float16)val[m];
      }
    }
  }
}

// one wave per node; lane handles channels {2*lane, 2*lane+1} (float2 vectorized)
__global__ __launch_bounds__(256) void k_gather(const float* __restrict__ m, const float* __restrict__ bias,
                                                const float* __restrict__ norm, const int* __restrict__ offs,
                                                const int* __restrict__ csr, float* __restrict__ hout,
                                                int ldc) {
  int w = threadIdx.x>>6, lane = threadIdx.x&63;
  int t = blockIdx.x*4 + w;
  float nt = norm[t];
  float cs = nt*nt;
  float2 mv = *(const float2*)&m[t*DD + 2*lane];
  float acc0 = mv.x*cs, acc1 = mv.y*cs;
  int e0 = offs[t], e1 = offs[t+1];
  for (int e=e0;e<e1;e++){
    int s = csr[e];
    float cf = norm[s]*nt;
    float2 sv = *(const float2*)&m[s*DD + 2*lane];
    acc0 += sv.x*cf;
    acc1 += sv.y*cf;
  }
  float2 bv = *(const float2*)&bias[2*lane];
  hout[(size_t)t*ldc + 2*lane]     = tanhf(acc0 + bv.x);
  hout[(size_t)t*ldc + 2*lane + 1] = tanhf(acc1 + bv.y);
}

// W2 = Wo @ (Wc[:128]+Wc[128:]);  b2 = bo @ (Wc[:128]+Wc[128:]) + bc
__global__ __launch_bounds__(256) void k_w2(const float* __restrict__ Wo, const float* __restrict__ bo,
                                            const float* __restrict__ Wc, const float* __restrict__ bc,
                                            float* __restrict__ W2, float* __restrict__ b2) {
  if (blockIdx.x < 64) {
    int gid = blockIdx.x*256 + threadIdx.x;
    int i = gid>>7, j = gid&127;
    float s = 0.f;
    for (int k2=0;k2<128;k2++)
      s += Wo[i*DD+k2]*(Wc[k2*DD+j] + Wc[(k2+128)*DD+j]);
    W2[i*DD+j] = s;
  } else if (threadIdx.x < 128) {
    int j = threadIdx.x;
    float s = bc[j];
    for (int k2=0;k2<128;k2++)
      s += bo[k2]*(Wc[k2*DD+j] + Wc[(k2+128)*DD+j]);
    b2[j] = s;
  }
}

// Read-once, double-buffered MFMA flash attention.
// Grid 256 = 64 q-tiles (BQ=128) x KSPLIT=4 (sp = bid&3 -> XCD-affine: each XCD's
// 1MB K/V slice stays L2-resident). Block: 512 threads = 8 waves = 2 q-halves x
// 4 k-slices; wave owns 64 q x 32 k-rows of each 128-row tile, own online (m,l,O).
// Double-buffered 64KB tiles: stage(t+1) issued before compute(t), __syncthreads
// drains vmcnt at tile end (T3-min). 4-slice LDS merge tree at the end; f16 Opart.
__global__ __launch_bounds__(512,2) void k_flash3(
    const _Float16* __restrict__ q16, const _Float16* __restrict__ k16f,
    const _Float16* __restrict__ vTf,
    _Float16* __restrict__ Opart, float* __restrict__ pm, float* __restrict__ pl)
{
  __shared__ union {
    struct { _Float16 K[2][16384]; _Float16 V[2][16384]; } s;  // 2 x (32K+32K)B
    float dump[4*8320];                                         // merge scratch (130-padded)
  } u;
  __shared__ float ml_m[8][64];
  __shared__ float ml_l[8][64];

  const int tid  = threadIdx.x;
  const int lane = tid & 63;
  const int w8   = tid >> 6;      // 0..7
  const int qh   = w8 >> 2;       // q-half
  const int ks   = w8 & 3;        // k-slice (owns rows [32ks,32ks+32) of each tile)
  const int l15  = lane & 15;
  const int g    = lane >> 4;
  const int qt   = blockIdx.x >> 2;
  const int sp   = blockIdx.x & 3;
  const int q0   = qt*128 + qh*64;

  // Q B-frags [qb][ds] in registers for the whole kernel
  hfrag qf[4][4];
  #pragma unroll
  for (int qb=0;qb<4;++qb)
    #pragma unroll
    for (int ds=0;ds<4;++ds)
      qf[qb][ds] = *(const hfrag*)&q16[(size_t)(q0+16*qb+l15)*DD + 32*ds + 8*g];

  float mrun[4], lrun[4];
  ffrag o[4][8];
  #pragma unroll
  for (int qb=0;qb<4;++qb){
    mrun[qb] = -1e30f; lrun[qb] = 0.f;
    #pragma unroll
    for (int nt=0;nt<8;++nt) o[qb][nt] = (ffrag){0.f,0.f,0.f,0.f};
  }

  const size_t base0 = (size_t)(sp*2048)*DD;   // slice start (f16 elems); tile = 128*DD
  // prologue: stage tile 0 into buf 0
  {
    const _Float16* Ks = k16f + base0;
    const _Float16* Vs = vTf  + base0;
    if (w8 < 4){
      #pragma unroll
      for (int i=0;i<8;++i) GLOAD16(Ks + (w8*8+i)*512 + lane*8, &u.s.K[0][(w8*8+i)*512]);
    } else {
      #pragma unroll
      for (int i=0;i<8;++i) GLOAD16(Vs + ((w8-4)*8+i)*512 + lane*8, &u.s.V[0][((w8-4)*8+i)*512]);
    }
  }
  __syncthreads();

  int cur = 0;
  for (int t=0; t<16; ++t){
    // issue next tile's staging (hides under this tile's compute)
    if (t < 15){
      const _Float16* Ks = k16f + base0 + (size_t)(t+1)*128*DD;
      const _Float16* Vs = vTf  + base0 + (size_t)(t+1)*128*DD;
      if (w8 < 4){
        #pragma unroll
        for (int i=0;i<8;++i) GLOAD16(Ks + (w8*8+i)*512 + lane*8, &u.s.K[cur^1][(w8*8+i)*512]);
      } else {
        #pragma unroll
        for (int i=0;i<8;++i) GLOAD16(Vs + ((w8-4)*8+i)*512 + lane*8, &u.s.V[cur^1][((w8-4)*8+i)*512]);
      }
    }

    // ---- S^T = K . Q^T over this wave's 32 k-rows ----
    ffrag s2[4][2];
    #pragma unroll
    for (int qb=0;qb<4;++qb){ s2[qb][0]=(ffrag){0.f,0.f,0.f,0.f}; s2[qb][1]=(ffrag){0.f,0.f,0.f,0.f}; }
    #pragma unroll
    for (int mt=0;mt<2;++mt)
      #pragma unroll
      for (int ds=0;ds<4;++ds){
        hfrag ka = *(const hfrag*)&u.s.K[cur][((ks*2+mt)*4+ds)*512 + lane*8];
        #pragma unroll
        for (int qb=0;qb<4;++qb)
          s2[qb][mt] = MFMA16(ka, qf[qb][ds], s2[qb][mt]);
      }

    // ---- online softmax (lane: 8 of the wave's 32 k for q-col l15) ----
    #pragma unroll
    for (int qb=0;qb<4;++qb){
      float tmax = -1e30f;
      #pragma unroll
      for (int mt=0;mt<2;++mt)
        tmax = fmaxf(tmax, fmaxf(fmaxf(s2[qb][mt][0], s2[qb][mt][1]),
                                 fmaxf(s2[qb][mt][2], s2[qb][mt][3])));
      tmax = fmaxf(tmax, __shfl_xor(tmax,16));
      tmax = fmaxf(tmax, __shfl_xor(tmax,32));
      const float mnew = fmaxf(mrun[qb], tmax);
      float psum = 0.f;
      #pragma unroll
      for (int mt=0;mt<2;++mt)
        #pragma unroll
        for (int r=0;r<4;++r){ float e = __expf(s2[qb][mt][r]-mnew); s2[qb][mt][r]=e; psum += e; }
      psum += __shfl_xor(psum,16);
      psum += __shfl_xor(psum,32);
      if (__any(mnew > mrun[qb])){
        const float sc = __expf(mrun[qb]-mnew);
        lrun[qb] = lrun[qb]*sc + psum;
        mrun[qb] = mnew;
        #pragma unroll
        for (int r=0;r<4;++r){
          const float scr = __shfl(sc, 4*g+r);
          #pragma unroll
          for (int nt=0;nt<8;++nt) o[qb][nt][r] *= scr;
        }
      } else {
        lrun[qb] += psum;
      }
    }

    // ---- PV: O += P.V over the wave's 32 k (single kappa chunk = ks) ----
    {
      hfrag pf[4];
      #pragma unroll
      for (int qb=0;qb<4;++qb)
        #pragma unroll
        for (int j=0;j<8;++j) pf[qb][j] = (_Float16)s2[qb][j>>2][j&3];
      #pragma unroll
      for (int nt=0;nt<8;++nt){
        hfrag vf = *(const hfrag*)&u.s.V[cur][(ks*8+nt)*512 + lane*8];
        #pragma unroll
        for (int qb=0;qb<4;++qb)
          o[qb][nt] = MFMA16(pf[qb], vf, o[qb][nt]);
      }
    }

    __syncthreads();     // drains vmcnt (stage t+1 landed) + all waves done reading buf[cur]
    cur ^= 1;
  }

  // ---- merge the 4 k-slices of each q-half (2 rounds), write f16 partials ----
  // R1 dump: ks 2,3 -> slots {qh*2, qh*2+1}
  if (ks >= 2){
    const int slot = qh*2 + (ks-2);
    #pragma unroll
    for (int qb=0;qb<4;++qb){
      #pragma unroll
      for (int r=0;r<4;++r){
        const int q = 16*qb + 4*g + r;
        #pragma unroll
        for (int nt=0;nt<8;++nt)
          u.dump[slot*8320 + q*130 + 16*nt + l15] = o[qb][nt][r];
      }
      if (g==0){ ml_m[w8][16*qb+l15] = mrun[qb]; ml_l[w8][16*qb+l15] = lrun[qb]; }
    }
  }
  __syncthreads();
  // R1 merge: ks 0,1 absorb ks+2
  if (ks < 2){
    const int yslot = qh*2 + ks;
    const int yw = w8 + 2;
    #pragma unroll
    for (int qb=0;qb<4;++qb){
      float mY = ml_m[yw][16*qb+l15], lY = ml_l[yw][16*qb+l15];
      float mn = fmaxf(mrun[qb], mY);
      float aX = __expf(mrun[qb]-mn), aY = __expf(mY-mn);
      lrun[qb] = lrun[qb]*aX + lY*aY;
      mrun[qb] = mn;
      #pragma unroll
      for (int r=0;r<4;++r){
        float axr = __shfl(aX, 4*g+r), ayr = __shfl(aY, 4*g+r);
        const int q = 16*qb + 4*g + r;
        #pragma unroll
        for (int nt=0;nt<8;++nt)
          o[qb][nt][r] = o[qb][nt][r]*axr + u.dump[yslot*8320 + q*130 + 16*nt + l15]*ayr;
      }
    }
  }
  __syncthreads();
  // R2 dump: ks=1 -> slot qh*2 (reuse), refreshed m,l
  if (ks == 1){
    const int slot = qh*2;
    #pragma unroll
    for (int qb=0;qb<4;++qb){
      #pragma unroll
      for (int r=0;r<4;++r){
        const int q = 16*qb + 4*g + r;
        #pragma unroll
        for (int nt=0;nt<8;++nt)
          u.dump[slot*8320 + q*130 + 16*nt + l15] = o[qb][nt][r];
      }
      if (g==0){ ml_m[w8][16*qb+l15] = mrun[qb]; ml_l[w8][16*qb+l15] = lrun[qb]; }
    }
  }
  __syncthreads();
  // R2 merge + global write: ks=0
  if (ks == 0){
    const int yslot = qh*2;
    const int yw = w8 + 1;
    #pragma unroll
    for (int qb=0;qb<4;++qb){
      float mY = ml_m[yw][16*qb+l15], lY = ml_l[yw][16*qb+l15];
      float mn = fmaxf(mrun[qb], mY);
      float aX = __expf(mrun[qb]-mn), aY = __expf(mY-mn);
      float lfin = lrun[qb]*aX + lY*aY;
      #pragma unroll
      for (int r=0;r<4;++r){
        float axr = __shfl(aX, 4*g+r), ayr = __shfl(aY, 4*g+r);
        const int q = 16*qb + 4*g + r;
        _Float16* dst = &Opart[((size_t)sp*TT + q0 + q)*DD];
        #pragma unroll
        for (int nt=0;nt<8;++nt)
          dst[16*nt + l15] = (_Float16)(o[qb][nt][r]*axr + u.dump[yslot*8320 + q*130 + 16*nt + l15]*ayr);
      }
      if (g==0){
        pm[sp*TT + q0 + 16*qb + l15] = mn;
        pl[sp*TT + q0 + 16*qb + l15] = lfin;
      }
    }
  }
}

// final GEMM with inline 4-split softmax combine on the A-load:
// A[t] = sum_s Opart_s[t]*u_s ; out[:,128:256] = A@W2 + b2
__global__ __launch_bounds__(256) void k_gemm_final(const _Float16* __restrict__ Opart,
                                                    const float* __restrict__ pm, const float* __restrict__ pl,
                                                    const float* __restrict__ W2, const float* __restrict__ b2,
                                                    float* __restrict__ out) {
  __shared__ float As[32*132];
  __shared__ float Ws[128*132];
  int tid = threadIdx.x;
  int row0 = blockIdx.x*32;
  #pragma unroll
  for (int i=0;i<4;i++){
    int idx = i*256+tid;
    int r = idx>>5, c4 = (idx&31)<<2;
    int t = row0 + r;
    float ms[4], ls[4];
    #pragma unroll
    for (int s=0;s<4;++s){ ms[s]=pm[s*TT+t]; ls[s]=pl[s*TT+t]; }
    float mx = fmaxf(fmaxf(ms[0],ms[1]), fmaxf(ms[2],ms[3]));
    float es[4]; float den = 0.f;
    #pragma unroll
    for (int s=0;s<4;++s){ es[s]=__expf(ms[s]-mx); den += ls[s]*es[s]; }
    float4 vv = {0.f,0.f,0.f,0.f};
    #pragma unroll
    for (int s=0;s<4;++s){
      float us = es[s]/den;
      h4 a = *(const h4*)&Opart[((size_t)s*TT + t)*DD + c4];
      vv.x += us*(float)a[0]; vv.y += us*(float)a[1];
      vv.z += us*(float)a[2]; vv.w += us*(float)a[3];
    }
    *(float4*)&As[r*132+c4] = vv;
  }
  #pragma unroll
  for (int i=0;i<16;i++){
    int idx = i*256+tid;
    int r = idx>>5, c4 = (idx&31)<<2;
    *(float4*)&Ws[r*132+c4] = *(const float4*)&W2[r*DD + c4];
  }
  __syncthreads();
  int rg = tid>>4, cg = tid&15;
  int r0 = rg*2, c0 = cg*8;
  float acc[2][8];
  #pragma unroll
  for (int a=0;a<2;a++)
    #pragma unroll
    for (int b=0;b<8;b++) acc[a][b]=0.f;
  for (int kk=0;kk<128;kk+=4){
    float a0[4], a1[4];
    *(float4*)a0 = *(float4*)&As[r0*132+kk];
    *(float4*)a1 = *(float4*)&As[(r0+1)*132+kk];
    #pragma unroll
    for (int j=0;j<4;j++){
      float w[8];
      *(float4*)&w[0] = *(float4*)&Ws[(kk+j)*132+c0];
      *(float4*)&w[4] = *(float4*)&Ws[(kk+j)*132+c0+4];
      #pragma unroll
      for (int m=0;m<8;m++){
        acc[0][m] += a0[j]*w[m];
        acc[1][m] += a1[j]*w[m];
      }
    }
  }
  #pragma unroll
  for (int a=0;a<2;a++){
    float outv[8];
    #pragma unroll
    for (int m=0;m<8;m++) outv[m] = acc[a][m] + b2[c0+m];
    float* dst = &out[(size_t)(row0+r0+a)*(2*DD) + DD + c0];
    *(float4*)&dst[0] = *(float4*)&outv[0];
    *(float4*)&dst[4] = *(float4*)&outv[4];
  }
}

extern "C" void kernel_launch(void* const* d_in, const int* in_sizes, int n_in,
                              void* d_out, int out_size, void* d_ws, size_t ws_size,
                              hipStream_t stream) {
  const float* x  = (const float*)d_in[0];
  const int* edges = (const int*)d_in[1];
  const float* Wg = (const float*)d_in[2];
  const float* bg = (const float*)d_in[3];
  const float* Wq = (const float*)d_in[4];
  const float* bq = (const float*)d_in[5];
  const float* Wk = (const float*)d_in[6];
  const float* bk = (const float*)d_in[7];
  const float* Wv = (const float*)d_in[8];
  const float* bv = (const float*)d_in[9];
  const float* Wo = (const float*)d_in[10];
  const float* bo = (const float*)d_in[11];
  const float* Wc = (const float*)d_in[12];
  const float* bc = (const float*)d_in[13];
  float* out = (float*)d_out;
  char* ws = (char*)d_ws;

  int* count = (int*)(ws + WS_COUNT);
  int* fill  = (int*)(ws + WS_FILL);
  int* offs  = (int*)(ws + WS_OFFS);
  float* norm = (float*)(ws + WS_NORM);
  int* csr   = (int*)(ws + WS_CSR);
  float* W2  = (float*)(ws + WS_W2);
  float* b2  = (float*)(ws + WS_B2);
  float* pm  = (float*)(ws + WS_PM);
  float* pl  = (float*)(ws + WS_PL);
  float* h0  = (float*)(ws + WS_H0);
  float* h1  = (float*)(ws + WS_H1);
  float* mbuf = (float*)(ws + WS_M);
  _Float16* Opart = (_Float16*)(ws + WS_OPART);
  // f16 buffers reuse the GCN scratch (GCN finishes before projections run)
  _Float16* q16 = (_Float16*)(ws + WS_H0);
  _Float16* k16 = (_Float16*)(ws + WS_H1);
  _Float16* vT  = (_Float16*)(ws + WS_M);

  // CSR build
  hipMemsetAsync(ws, 0, 64u<<10, stream);   // count + fill
  k_count<<<NEDGE/256,256,0,stream>>>(edges, count);
  k_scan<<<1,1024,0,stream>>>(count, offs, norm);
  k_fill<<<NEDGE/256,256,0,stream>>>(edges, offs, fill, csr);

  // GCN: x -> h0 -> h1 -> h0 -> out[:, :128]
  const float* cur = x;
  float* hb[2] = {h0, h1};
  for (int l=0; l<4; ++l) {
    k_gemm<<<256,256,0,stream>>>(cur, Wg + l*DD*DD, nullptr, mbuf, DD, 0);
    float* nxt; int ldc;
    if (l < 3) { nxt = hb[l&1]; ldc = DD; } else { nxt = out; ldc = 2*DD; }
    k_gather<<<TT/4,256,0,stream>>>(mbuf, bg + l*DD, norm, offs, csr, nxt, ldc);
    cur = nxt;
  }

  // projections (merged QKV launch, f16 fragment-order outputs) + fused output weight
  k_proj3<<<768,256,0,stream>>>(x, Wq, bq, Wk, bk, Wv, bv, q16, k16, vT);
  k_w2<<<65,256,0,stream>>>(Wo, bo, Wc, bc, W2, b2);

  k_flash3<<<256,512,0,stream>>>(q16, k16, vT, Opart, pm, pl);
  k_gemm_final<<<256,256,0,stream>>>(Opart, pm, pl, W2, b2, out);
}

// Round 6
// 221.841 us; speedup vs baseline: 1.2624x; 1.2624x over previous
//
#include <hip/hip_runtime.h>
#include <math.h>

#define TT 8192
#define DD 128
#define GB 64
#define GN 128
#define GE 2048
#define NEDGE (GB*GE)   // 131072

// ---- workspace layout (bytes) ----
#define WS_COUNT   0u            // 8192 int
#define WS_FILL    (32u<<10)     // 8192 int
#define WS_OFFS    (64u<<10)     // 8193 int
#define WS_NORM    (100u<<10)    // 8192 f32
#define WS_CSR     (132u<<10)    // 131072 int
#define WS_W2      (644u<<10)    // 128*128 f32
#define WS_B2      (708u<<10)    // 128 f32
// GCN f32 scratch (live only during GCN):
#define WS_H0      (1u<<20)      // 4MB
#define WS_H1      (5u<<20)      // 4MB
#define WS_M       (9u<<20)      // 4MB
// attention buffers (written after GCN finishes; overlap GCN scratch):
#define WS_Q16     (1u<<20)      // 2MB f16
#define WS_K16     (3u<<20)      // 2MB f16 frag-order
#define WS_VT      (5u<<20)      // 2MB f16 frag-order (kappa)
#define WS_OPART   (7u<<20)      // 16MB: 8 x 8192 x 128 f16 partials
#define WS_PM      (23u<<20)     // 8*8192 f32 (256K)
#define WS_PL      ((23u<<20)+(256u<<10))
// total 23.5MB (within the 25MB proven-safe footprint)

typedef _Float16 hfrag  __attribute__((ext_vector_type(8)));
typedef _Float16 h4     __attribute__((ext_vector_type(4)));
typedef float    ffrag  __attribute__((ext_vector_type(4)));

#define MFMA16(a,b,c) __builtin_amdgcn_mfma_f32_16x16x32_f16((a),(b),(c),0,0,0)

typedef __attribute__((address_space(1))) unsigned int gu32_t;
typedef __attribute__((address_space(3))) unsigned int lu32_t;
#define GLOAD16(gp, lp) __builtin_amdgcn_global_load_lds((gu32_t*)(const void*)(gp), (lu32_t*)(void*)(lp), 16, 0, 0)

__global__ __launch_bounds__(256) void k_count(const int* __restrict__ edges, int* __restrict__ count) {
  int e = blockIdx.x*256 + threadIdx.x;
  int b = e >> 11;
  int i = e & 2047;
  int dst = edges[b*2*GE + GE + i] + b*GN;
  atomicAdd(&count[dst], 1);
}

__global__ __launch_bounds__(1024) void k_scan(const int* __restrict__ count, int* __restrict__ offs,
                                               float* __restrict__ norm) {
  __shared__ int lds[1024];
  int tid = threadIdx.x;
  int base = tid*8;
  int loc[8]; int tot = 0;
  #pragma unroll
  for (int j=0;j<8;j++){ loc[j]=count[base+j]; tot+=loc[j]; }
  lds[tid]=tot; __syncthreads();
  for (int s=1;s<1024;s<<=1){
    int v = (tid>=s)? lds[tid-s] : 0;
    __syncthreads();
    lds[tid]+=v;
    __syncthreads();
  }
  int ex = lds[tid]-tot;
  #pragma unroll
  for (int j=0;j<8;j++){
    offs[base+j]=ex; ex+=loc[j];
    norm[base+j]=rsqrtf(1.0f+(float)loc[j]);
  }
  if (tid==1023) offs[TT]=ex;
}

__global__ __launch_bounds__(256) void k_fill(const int* __restrict__ edges, const int* __restrict__ offs,
                                              int* __restrict__ fill, int* __restrict__ csr) {
  int e = blockIdx.x*256+threadIdx.x;
  int b = e>>11, i = e&2047;
  int s = edges[b*2*GE + i] + b*GN;
  int d = edges[b*2*GE + GE + i] + b*GN;
  int pos = offs[d] + atomicAdd(&fill[d],1);
  csr[pos] = s;
}

// C[M,128] = A[M,128] @ W[128,128] (+bias), written at C[row*ldc + cofs + col]
__global__ __launch_bounds__(256) void k_gemm(const float* __restrict__ A, const float* __restrict__ W,
                                              const float* __restrict__ bias, float* __restrict__ C,
                                              int ldc, int cofs) {
  __shared__ float As[32*132];
  __shared__ float Ws[128*132];
  int tid = threadIdx.x;
  int row0 = blockIdx.x*32;
  #pragma unroll
  for (int i=0;i<4;i++){
    int idx = i*256+tid;
    int r = idx>>5, c4 = (idx&31)<<2;
    *(float4*)&As[r*132+c4] = *(const float4*)&A[(row0+r)*DD + c4];
  }
  #pragma unroll
  for (int i=0;i<16;i++){
    int idx = i*256+tid;
    int r = idx>>5, c4 = (idx&31)<<2;
    *(float4*)&Ws[r*132+c4] = *(const float4*)&W[r*DD + c4];
  }
  __syncthreads();
  int rg = tid>>4, cg = tid&15;
  int r0 = rg*2, c0 = cg*8;
  float acc[2][8];
  #pragma unroll
  for (int a=0;a<2;a++)
    #pragma unroll
    for (int b=0;b<8;b++) acc[a][b]=0.f;
  for (int kk=0;kk<128;kk+=4){
    float a0[4], a1[4];
    *(float4*)a0 = *(float4*)&As[r0*132+kk];
    *(float4*)a1 = *(float4*)&As[(r0+1)*132+kk];
    #pragma unroll
    for (int j=0;j<4;j++){
      float w[8];
      *(float4*)&w[0] = *(float4*)&Ws[(kk+j)*132+c0];
      *(float4*)&w[4] = *(float4*)&Ws[(kk+j)*132+c0+4];
      #pragma unroll
      for (int m=0;m<8;m++){
        acc[0][m] += a0[j]*w[m];
        acc[1][m] += a1[j]*w[m];
      }
    }
  }
  #pragma unroll
  for (int a=0;a<2;a++){
    float outv[8];
    #pragma unroll
    for (int m=0;m<8;m++)
      outv[m] = acc[a][m] + (bias ? bias[c0+m] : 0.f);
    float* dst = &C[(size_t)(row0+r0+a)*ldc + cofs + c0];
    *(float4*)&dst[0] = *(float4*)&outv[0];
    *(float4*)&dst[4] = *(float4*)&outv[4];
  }
}

// merged Q/K/V projections -> f16, one launch, grid 768.
// mode 0 (Q): q16[row][d]                              (plain)
// mode 1 (K): fragment-order: elem ((R*4+ds)*64 + (row&15) + 16*g)*8 + j, R=row/16
// mode 2 (V): V^T fragment-order with PV k-permutation kappa(g,j)=16*(j>>2)+4g+(j&3):
//             elem ((C*8 + nt)*64 + (d&15) + 16*gx)*8 + jx, C=row/32, nt=d/16,
//             gx=(kloc&15)>>2, jx=((kloc>>4)<<2)|(kloc&3), kloc=row&31
__global__ __launch_bounds__(256) void k_proj3(const float* __restrict__ A,
                                               const float* __restrict__ Wq, const float* __restrict__ bq_,
                                               const float* __restrict__ Wk, const float* __restrict__ bk_,
                                               const float* __restrict__ Wv, const float* __restrict__ bv_,
                                               _Float16* __restrict__ q16,
                                               _Float16* __restrict__ k16,
                                               _Float16* __restrict__ vT) {
  __shared__ float As[32*132];
  __shared__ float Ws[128*132];
  const int mode = blockIdx.x >> 8;
  const int row0 = (blockIdx.x & 255) * 32;
  const float* W    = (mode==0) ? Wq : (mode==1) ? Wk : Wv;
  const float* bias = (mode==0) ? bq_ : (mode==1) ? bk_ : bv_;
  int tid = threadIdx.x;
  #pragma unroll
  for (int i=0;i<4;i++){
    int idx = i*256+tid;
    int r = idx>>5, c4 = (idx&31)<<2;
    *(float4*)&As[r*132+c4] = *(const float4*)&A[(row0+r)*DD + c4];
  }
  #pragma unroll
  for (int i=0;i<16;i++){
    int idx = i*256+tid;
    int r = idx>>5, c4 = (idx&31)<<2;
    *(float4*)&Ws[r*132+c4] = *(const float4*)&W[r*DD + c4];
  }
  __syncthreads();
  int rg = tid>>4, cg = tid&15;
  int r0 = rg*2, c0 = cg*8;
  float acc[2][8];
  #pragma unroll
  for (int a=0;a<2;a++)
    #pragma unroll
    for (int b=0;b<8;b++) acc[a][b]=0.f;
  for (int kk=0;kk<128;kk+=4){
    float a0[4], a1[4];
    *(float4*)a0 = *(float4*)&As[r0*132+kk];
    *(float4*)a1 = *(float4*)&As[(r0+1)*132+kk];
    #pragma unroll
    for (int j=0;j<4;j++){
      float w[8];
      *(float4*)&w[0] = *(float4*)&Ws[(kk+j)*132+c0];
      *(float4*)&w[4] = *(float4*)&Ws[(kk+j)*132+c0+4];
      #pragma unroll
      for (int m=0;m<8;m++){
        acc[0][m] += a0[j]*w[m];
        acc[1][m] += a1[j]*w[m];
      }
    }
  }
  #pragma unroll
  for (int a=0;a<2;a++){
    int row = row0 + r0 + a;
    float val[8];
    #pragma unroll
    for (int m=0;m<8;m++) val[m] = acc[a][m] + bias[c0+m];
    if (mode == 0) {
      hfrag t;
      #pragma unroll
      for (int m=0;m<8;m++) t[m] = (_Float16)val[m];
      *(hfrag*)&q16[(size_t)row*DD + c0] = t;
    } else if (mode == 1) {
      hfrag t;
      #pragma unroll
      for (int m=0;m<8;m++) t[m] = (_Float16)val[m];
      int R = row>>4, l15r = row&15, dsx = cg>>2, gx = cg&3;
      *(hfrag*)&k16[((size_t)(R*4+dsx)*64 + l15r + 16*gx)*8] = t;
    } else {
      int C = row>>5, kloc = row&31;
      int gx = (kloc&15)>>2;
      int jx = ((kloc>>4)<<2) | (kloc&3);
      #pragma unroll
      for (int m=0;m<8;m++){
        int d = c0+m;
        vT[((size_t)(C*8 + (d>>4))*64 + (d&15) + 16*gx)*8 + jx] = (_Float16)val[m];
      }
    }
  }
}

// one wave per node; lane handles channels {2*lane, 2*lane+1} (float2 vectorized)
__global__ __launch_bounds__(256) void k_gather(const float* __restrict__ m, const float* __restrict__ bias,
                                                const float* __restrict__ norm, const int* __restrict__ offs,
                                                const int* __restrict__ csr, float* __restrict__ hout,
                                                int ldc) {
  int w = threadIdx.x>>6, lane = threadIdx.x&63;
  int t = blockIdx.x*4 + w;
  float nt = norm[t];
  float cs = nt*nt;
  float2 mv = *(const float2*)&m[t*DD + 2*lane];
  float acc0 = mv.x*cs, acc1 = mv.y*cs;
  int e0 = offs[t], e1 = offs[t+1];
  for (int e=e0;e<e1;e++){
    int s = csr[e];
    float cf = norm[s]*nt;
    float2 sv = *(const float2*)&m[s*DD + 2*lane];
    acc0 += sv.x*cf;
    acc1 += sv.y*cf;
  }
  float2 bv = *(const float2*)&bias[2*lane];
  hout[(size_t)t*ldc + 2*lane]     = tanhf(acc0 + bv.x);
  hout[(size_t)t*ldc + 2*lane + 1] = tanhf(acc1 + bv.y);
}

// W2 = Wo @ (Wc[:128]+Wc[128:]);  b2 = bo @ (Wc[:128]+Wc[128:]) + bc
__global__ __launch_bounds__(256) void k_w2(const float* __restrict__ Wo, const float* __restrict__ bo,
                                            const float* __restrict__ Wc, const float* __restrict__ bc,
                                            float* __restrict__ W2, float* __restrict__ b2) {
  if (blockIdx.x < 64) {
    int gid = blockIdx.x*256 + threadIdx.x;
    int i = gid>>7, j = gid&127;
    float s = 0.f;
    for (int k2=0;k2<128;k2++)
      s += Wo[i*DD+k2]*(Wc[k2*DD+j] + Wc[(k2+128)*DD+j]);
    W2[i*DD+j] = s;
  } else if (threadIdx.x < 128) {
    int j = threadIdx.x;
    float s = bc[j];
    for (int k2=0;k2<128;k2++)
      s += bo[k2]*(Wc[k2*DD+j] + Wc[(k2+128)*DD+j]);
    b2[j] = s;
  }
}

// 8-warp independent-softmax MFMA flash attention (m214 structure).
// Grid 256 = 32 q-tiles x KSPLIT=8 (sp = bid&7 -> XCD-affine; each XCD's 512KB
// K/V slice is L2-resident). Block: 512 threads = 8 warps; warp w8 owns 32 q-rows
// (q0 = qt*256 + w8*32) with a fully independent online softmax over the slice's
// 1024 k (16 tiles of 64). K/V double-buffered LDS (64KB), shared read-only by
// all warps. No cross-wave merging; 8 global partials combined in k_gemm_final.
__global__ __launch_bounds__(512,2) void k_flash4(
    const _Float16* __restrict__ q16, const _Float16* __restrict__ k16f,
    const _Float16* __restrict__ vTf,
    _Float16* __restrict__ Opart, float* __restrict__ pm, float* __restrict__ pl)
{
  __shared__ _Float16 Kb[2][8192];   // 16KB per buf
  __shared__ _Float16 Vb[2][8192];
  const int tid  = threadIdx.x;
  const int lane = tid & 63;
  const int w8   = tid >> 6;
  const int l15  = lane & 15;
  const int g    = lane >> 4;
  const int qt   = blockIdx.x >> 3;
  const int sp   = blockIdx.x & 7;
  const int q0   = qt*256 + w8*32;

  // Q B-frags (2 x 16-q groups), resident all kernel
  hfrag qf[2][4];
  #pragma unroll
  for (int qb=0;qb<2;++qb)
    #pragma unroll
    for (int ds=0;ds<4;++ds)
      qf[qb][ds] = *(const hfrag*)&q16[(size_t)(q0+16*qb+l15)*DD + 32*ds + 8*g];

  float mrun[2] = {-1e30f,-1e30f}, lrun[2] = {0.f,0.f};
  ffrag o[2][8];
  #pragma unroll
  for (int qb=0;qb<2;++qb)
    #pragma unroll
    for (int nt=0;nt<8;++nt) o[qb][nt] = (ffrag){0.f,0.f,0.f,0.f};

  const size_t kbase = (size_t)(sp*1024)*DD;
  // prologue: stage tile 0
  {
    const _Float16* Ks = k16f + kbase;
    const _Float16* Vs = vTf  + kbase;
    #pragma unroll
    for (int j=0;j<2;++j){
      const int c = w8*2 + j;
      GLOAD16(Ks + c*512 + lane*8, &Kb[0][c*512]);
      GLOAD16(Vs + c*512 + lane*8, &Vb[0][c*512]);
    }
  }
  __syncthreads();

  int cur = 0;
  for (int t=0; t<16; ++t){
    // issue next tile's staging early (lands under this tile's compute)
    if (t < 15){
      const _Float16* Ks = k16f + kbase + (size_t)(t+1)*64*DD;
      const _Float16* Vs = vTf  + kbase + (size_t)(t+1)*64*DD;
      #pragma unroll
      for (int j=0;j<2;++j){
        const int c = w8*2 + j;
        GLOAD16(Ks + c*512 + lane*8, &Kb[cur^1][c*512]);
        GLOAD16(Vs + c*512 + lane*8, &Vb[cur^1][c*512]);
      }
    }

    // ---- S^T = K . Q^T (64 k x 32 q) ----
    ffrag s2[2][4];
    #pragma unroll
    for (int qb=0;qb<2;++qb)
      #pragma unroll
      for (int mt=0;mt<4;++mt) s2[qb][mt] = (ffrag){0.f,0.f,0.f,0.f};
    __builtin_amdgcn_s_setprio(1);
    #pragma unroll
    for (int mt=0;mt<4;++mt)
      #pragma unroll
      for (int ds=0;ds<4;++ds){
        hfrag kf = *(const hfrag*)&Kb[cur][(mt*4+ds)*512 + lane*8];
        s2[0][mt] = MFMA16(kf, qf[0][ds], s2[0][mt]);
        s2[1][mt] = MFMA16(kf, qf[1][ds], s2[1][mt]);
      }
    __builtin_amdgcn_s_setprio(0);

    // ---- online softmax: per qb, lane holds 16 of 64 k for q-col l15 ----
    #pragma unroll
    for (int qb=0;qb<2;++qb){
      float tmax = -1e30f;
      #pragma unroll
      for (int mt=0;mt<4;++mt)
        tmax = fmaxf(tmax, fmaxf(fmaxf(s2[qb][mt][0], s2[qb][mt][1]),
                                 fmaxf(s2[qb][mt][2], s2[qb][mt][3])));
      tmax = fmaxf(tmax, __shfl_xor(tmax,16));
      tmax = fmaxf(tmax, __shfl_xor(tmax,32));
      const float mnew = fmaxf(mrun[qb], tmax);
      float psum = 0.f;
      #pragma unroll
      for (int mt=0;mt<4;++mt)
        #pragma unroll
        for (int r=0;r<4;++r){ float e = __expf(s2[qb][mt][r]-mnew); s2[qb][mt][r]=e; psum += e; }
      psum += __shfl_xor(psum,16);
      psum += __shfl_xor(psum,32);
      if (__any(mnew > mrun[qb])){
        const float sc = __expf(mrun[qb]-mnew);
        lrun[qb] = lrun[qb]*sc + psum;
        mrun[qb] = mnew;
        #pragma unroll
        for (int r=0;r<4;++r){
          const float scr = __shfl(sc, 4*g+r);
          #pragma unroll
          for (int nt=0;nt<8;++nt) o[qb][nt][r] *= scr;
        }
      } else {
        lrun[qb] += psum;
      }
    }

    // ---- PV: O += P.V over the tile's two 32-k kappa chunks ----
    __builtin_amdgcn_s_setprio(1);
    #pragma unroll
    for (int c2=0;c2<2;++c2){
      hfrag pf0, pf1;
      #pragma unroll
      for (int j=0;j<8;++j){
        pf0[j] = (_Float16)s2[0][2*c2+(j>>2)][j&3];
        pf1[j] = (_Float16)s2[1][2*c2+(j>>2)][j&3];
      }
      #pragma unroll
      for (int nt=0;nt<8;++nt){
        hfrag vf = *(const hfrag*)&Vb[cur][(c2*8+nt)*512 + lane*8];
        o[0][nt] = MFMA16(pf0, vf, o[0][nt]);
        o[1][nt] = MFMA16(pf1, vf, o[1][nt]);
      }
    }
    __builtin_amdgcn_s_setprio(0);

    __syncthreads();     // all warps done with buf[cur]; next staging landed
    cur ^= 1;
  }

  // ---- per-warp epilogue (no merging needed) ----
  #pragma unroll
  for (int qb=0;qb<2;++qb){
    #pragma unroll
    for (int r=0;r<4;++r){
      _Float16* dst = &Opart[((size_t)sp*TT + q0 + 16*qb + 4*g + r)*DD];
      #pragma unroll
      for (int nt=0;nt<8;++nt)
        dst[16*nt + l15] = (_Float16)o[qb][nt][r];
    }
    if (g==0){
      pm[(size_t)sp*TT + q0 + 16*qb + l15] = mrun[qb];
      pl[(size_t)sp*TT + q0 + 16*qb + l15] = lrun[qb];
    }
  }
}

// final GEMM with inline 8-split softmax combine on the A-load:
// A[t] = sum_s Opart_s[t]*u_s ; out[:,128:256] = A@W2 + b2
__global__ __launch_bounds__(256) void k_gemm_final(const _Float16* __restrict__ Opart,
                                                    const float* __restrict__ pm, const float* __restrict__ pl,
                                                    const float* __restrict__ W2, const float* __restrict__ b2,
                                                    float* __restrict__ out) {
  __shared__ float As[32*132];
  __shared__ float Ws[128*132];
  int tid = threadIdx.x;
  int row0 = blockIdx.x*32;
  #pragma unroll
  for (int i=0;i<4;i++){
    int idx = i*256+tid;
    int r = idx>>5, c4 = (idx&31)<<2;
    int t = row0 + r;
    float ms[8], ls[8];
    #pragma unroll
    for (int s=0;s<8;++s){ ms[s]=pm[(size_t)s*TT+t]; ls[s]=pl[(size_t)s*TT+t]; }
    float mx = ms[0];
    #pragma unroll
    for (int s=1;s<8;++s) mx = fmaxf(mx, ms[s]);
    float es[8]; float den = 0.f;
    #pragma unroll
    for (int s=0;s<8;++s){ es[s]=__expf(ms[s]-mx); den += ls[s]*es[s]; }
    float4 vv = {0.f,0.f,0.f,0.f};
    #pragma unroll
    for (int s=0;s<8;++s){
      float us = es[s]/den;
      h4 a = *(const h4*)&Opart[((size_t)s*TT + t)*DD + c4];
      vv.x += us*(float)a[0]; vv.y += us*(float)a[1];
      vv.z += us*(float)a[2]; vv.w += us*(float)a[3];
    }
    *(float4*)&As[r*132+c4] = vv;
  }
  #pragma unroll
  for (int i=0;i<16;i++){
    int idx = i*256+tid;
    int r = idx>>5, c4 = (idx&31)<<2;
    *(float4*)&Ws[r*132+c4] = *(const float4*)&W2[r*DD + c4];
  }
  __syncthreads();
  int rg = tid>>4, cg = tid&15;
  int r0 = rg*2, c0 = cg*8;
  float acc[2][8];
  #pragma unroll
  for (int a=0;a<2;a++)
    #pragma unroll
    for (int b=0;b<8;b++) acc[a][b]=0.f;
  for (int kk=0;kk<128;kk+=4){
    float a0[4], a1[4];
    *(float4*)a0 = *(float4*)&As[r0*132+kk];
    *(float4*)a1 = *(float4*)&As[(r0+1)*132+kk];
    #pragma unroll
    for (int j=0;j<4;j++){
      float w[8];
      *(float4*)&w[0] = *(float4*)&Ws[(kk+j)*132+c0];
      *(float4*)&w[4] = *(float4*)&Ws[(kk+j)*132+c0+4];
      #pragma unroll
      for (int m=0;m<8;m++){
        acc[0][m] += a0[j]*w[m];
        acc[1][m] += a1[j]*w[m];
      }
    }
  }
  #pragma unroll
  for (int a=0;a<2;a++){
    float outv[8];
    #pragma unroll
    for (int m=0;m<8;m++) outv[m] = acc[a][m] + b2[c0+m];
    float* dst = &out[(size_t)(row0+r0+a)*(2*DD) + DD + c0];
    *(float4*)&dst[0] = *(float4*)&outv[0];
    *(float4*)&dst[4] = *(float4*)&outv[4];
  }
}

extern "C" void kernel_launch(void* const* d_in, const int* in_sizes, int n_in,
                              void* d_out, int out_size, void* d_ws, size_t ws_size,
                              hipStream_t stream) {
  const float* x  = (const float*)d_in[0];
  const int* edges = (const int*)d_in[1];
  const float* Wg = (const float*)d_in[2];
  const float* bg = (const float*)d_in[3];
  const float* Wq = (const float*)d_in[4];
  const float* bq = (const float*)d_in[5];
  const float* Wk = (const float*)d_in[6];
  const float* bk = (const float*)d_in[7];
  const float* Wv = (const float*)d_in[8];
  const float* bv = (const float*)d_in[9];
  const float* Wo = (const float*)d_in[10];
  const float* bo = (const float*)d_in[11];
  const float* Wc = (const float*)d_in[12];
  const float* bc = (const float*)d_in[13];
  float* out = (float*)d_out;
  char* ws = (char*)d_ws;

  int* count = (int*)(ws + WS_COUNT);
  int* fill  = (int*)(ws + WS_FILL);
  int* offs  = (int*)(ws + WS_OFFS);
  float* norm = (float*)(ws + WS_NORM);
  int* csr   = (int*)(ws + WS_CSR);
  float* W2  = (float*)(ws + WS_W2);
  float* b2  = (float*)(ws + WS_B2);
  float* pm  = (float*)(ws + WS_PM);
  float* pl  = (float*)(ws + WS_PL);
  float* h0  = (float*)(ws + WS_H0);
  float* h1  = (float*)(ws + WS_H1);
  float* mbuf = (float*)(ws + WS_M);
  _Float16* Opart = (_Float16*)(ws + WS_OPART);
  // f16 buffers overwrite GCN scratch only after GCN kernels have been enqueued
  _Float16* q16 = (_Float16*)(ws + WS_Q16);
  _Float16* k16 = (_Float16*)(ws + WS_K16);
  _Float16* vT  = (_Float16*)(ws + WS_VT);

  // CSR build
  hipMemsetAsync(ws, 0, 64u<<10, stream);   // count + fill
  k_count<<<NEDGE/256,256,0,stream>>>(edges, count);
  k_scan<<<1,1024,0,stream>>>(count, offs, norm);
  k_fill<<<NEDGE/256,256,0,stream>>>(edges, offs, fill, csr);

  // GCN: x -> h0 -> h1 -> h0 -> out[:, :128]
  const float* cur = x;
  float* hb[2] = {h0, h1};
  for (int l=0; l<4; ++l) {
    k_gemm<<<256,256,0,stream>>>(cur, Wg + l*DD*DD, nullptr, mbuf, DD, 0);
    float* nxt; int ldc;
    if (l < 3) { nxt = hb[l&1]; ldc = DD; } else { nxt = out; ldc = 2*DD; }
    k_gather<<<TT/4,256,0,stream>>>(mbuf, bg + l*DD, norm, offs, csr, nxt, ldc);
    cur = nxt;
  }

  // projections (merged QKV launch, f16 fragment-order outputs) + fused output weight
  k_proj3<<<768,256,0,stream>>>(x, Wq, bq, Wk, bk, Wv, bv, q16, k16, vT);
  k_w2<<<65,256,0,stream>>>(Wo, bo, Wc, bc, W2, b2);

  k_flash4<<<256,512,0,stream>>>(q16, k16, vT, Opart, pm, pl);
  k_gemm_final<<<256,256,0,stream>>>(Opart, pm, pl, W2, b2, out);
}

// Round 7
// 136.534 us; speedup vs baseline: 2.0511x; 1.6248x over previous
//
#include <hip/hip_runtime.h>
#include <math.h>

#define TT 8192
#define DD 128
#define GB 64
#define GN 128
#define GE 2048
#define NEDGE (GB*GE)   // 131072

// ---- workspace layout (bytes) ----
#define WS_W2      (644u<<10)    // 128*128 f32
#define WS_B2      (708u<<10)    // 128 f32
#define WS_Q16     (1u<<20)      // 2MB f16
#define WS_K16     (3u<<20)      // 2MB f16 frag-order
#define WS_VT      (5u<<20)      // 2MB f16 frag-order (kappa)
#define WS_OPART   (7u<<20)      // 16MB: 8 x 8192 x 128 f16 partials
#define WS_PM      (23u<<20)     // 8*8192 f32 (256K)
#define WS_PL      ((23u<<20)+(256u<<10))

typedef _Float16 hfrag  __attribute__((ext_vector_type(8)));
typedef _Float16 h4     __attribute__((ext_vector_type(4)));
typedef float    ffrag  __attribute__((ext_vector_type(4)));

#define MFMA16(a,b,c) __builtin_amdgcn_mfma_f32_16x16x32_f16((a),(b),(c),0,0,0)

typedef __attribute__((address_space(1))) unsigned int gu32_t;
typedef __attribute__((address_space(3))) unsigned int lu32_t;
#define GLOAD16(gp, lp) __builtin_amdgcn_global_load_lds((gu32_t*)(const void*)(gp), (lu32_t*)(void*)(lp), 16, 0, 0)

// fragment-order element index (proven by flash4's k16/vT layouts):
// A-operand frag = fidx(i,k); B-operand frag = fidx(j,k); read as buf[f*512+lane*8]
__device__ __forceinline__ int fidx(int r_, int c_) {
  return (((r_>>4)*4 + (c_>>5))*64 + (r_&15) + 16*((c_>>3)&3))*8 + (c_&7);
}

__device__ __forceinline__ float tanh_fast(float x) {
  float e = __expf(2.f*x);
  return 1.f - 2.f/(e+1.f);
}

// ---------------- fused per-graph GCN (CSR + 4 layers, all in LDS) --------------
// One block per graph (grid 64, 512 threads = 8 waves). Adjacency densified once:
// Af[dst][src] = sum coef (f32 LDS atomics), converted to A-frag-order f16.
// Per layer: m^T = Wg^T (A) x h (B)  [MFMA], h' = tanh(A_hat (A) x m (B) + bg) [MFMA].
// Layer 3 writes out[:, :128] directly.
__global__ __launch_bounds__(512,1) void k_gcn(const float* __restrict__ x,
                                               const int* __restrict__ edges,
                                               const float* __restrict__ Wg,
                                               const float* __restrict__ bg,
                                               float* __restrict__ out) {
  __shared__ __align__(16) char Lm[132096];
  float*    Af  = (float*)Lm;                     // 64KB @0 (temporary)
  _Float16* W16 = (_Float16*)Lm;                  // 32KB @0     (overlays Af after convert)
  _Float16* m16 = (_Float16*)(Lm + 32768);        // 32KB @32K   (overlays Af)
  _Float16* h16 = (_Float16*)(Lm + 65536);        // 32KB @64K
  _Float16* A16 = (_Float16*)(Lm + 98304);        // 32KB @96K
  int*      cnt = (int*)(Lm + 131072);            // 512B
  float*    nrm = (float*)(Lm + 131584);          // 512B

  const int tid  = threadIdx.x;
  const int lane = tid & 63;
  const int w8   = tid >> 6;
  const int l15  = lane & 15;
  const int g    = lane >> 4;
  const int wi   = w8 >> 2;        // i-tile half (4 tiles each)
  const int wj   = w8 & 3;         // j-group quarter (2 groups each)
  const int b    = blockIdx.x;
  const int* eg  = edges + b*2*GE;

  // zero Af + cnt
  #pragma unroll
  for (int i=0;i<8;++i) ((float4*)Af)[i*512 + tid] = (float4){0.f,0.f,0.f,0.f};
  if (tid < 128) cnt[tid] = 0;
  __syncthreads();
  // degree count
  #pragma unroll
  for (int i=0;i<4;++i) atomicAdd(&cnt[eg[GE + i*512 + tid]], 1);
  __syncthreads();
  if (tid < 128) nrm[tid] = rsqrtf(1.f + (float)cnt[tid]);
  __syncthreads();
  // densified adjacency (f32 LDS atomics), then self-loops
  #pragma unroll
  for (int i=0;i<4;++i){
    int s = eg[i*512 + tid], d = eg[GE + i*512 + tid];
    atomicAdd(&Af[d*128 + s], nrm[s]*nrm[d]);
  }
  __syncthreads();
  if (tid < 128) Af[tid*128 + tid] += nrm[tid]*nrm[tid];
  __syncthreads();
  // convert A_hat -> A-frag-order f16 (A16), then Af region is free
  #pragma unroll
  for (int i=0;i<8;++i){
    int i4 = i*512 + tid;
    float4 v = ((const float4*)Af)[i4];
    int dst = i4>>5, s4 = (i4&31)<<2;
    h4 t; t[0]=(_Float16)v.x; t[1]=(_Float16)v.y; t[2]=(_Float16)v.z; t[3]=(_Float16)v.w;
    *(h4*)&A16[fidx(dst, s4)] = t;
  }
  // load x -> h16 (B-frag order)
  #pragma unroll
  for (int i=0;i<8;++i){
    int i4 = i*512 + tid;
    int n = i4>>5, k4 = (i4&31)<<2;
    float4 v = *(const float4*)&x[((size_t)b*128 + n)*128 + k4];
    h4 t; t[0]=(_Float16)v.x; t[1]=(_Float16)v.y; t[2]=(_Float16)v.z; t[3]=(_Float16)v.w;
    *(h4*)&h16[fidx(n, k4)] = t;
  }
  __syncthreads();

  for (int l=0; l<4; ++l){
    // stage Wg[l]^T -> W16 A-frag-order: W16[fidx(dout,k)] = Wg[k][dout]
    const float* Wl = Wg + l*DD*DD;
    #pragma unroll
    for (int i=0;i<8;++i){
      int i4 = i*512 + tid;
      int k = i4>>5, i0 = (i4&31)<<2;
      float4 v = *(const float4*)&Wl[k*DD + i0];
      W16[fidx(i0+0,k)] = (_Float16)v.x;
      W16[fidx(i0+1,k)] = (_Float16)v.y;
      W16[fidx(i0+2,k)] = (_Float16)v.z;
      W16[fidx(i0+3,k)] = (_Float16)v.w;
    }
    __syncthreads();

    // GEMM1: D1[dout][n] = sum_k Wg[k][dout] h[n][k]  -> m16 (B2-frag order)
    {
      hfrag bf[2][4];
      #pragma unroll
      for (int jj=0;jj<2;++jj){
        const int jg = wj*2+jj;
        #pragma unroll
        for (int ds=0;ds<4;++ds) bf[jj][ds] = *(const hfrag*)&h16[(jg*4+ds)*512 + lane*8];
      }
      #pragma unroll
      for (int it=0;it<4;++it){
        const int Ri = wi*4+it;
        hfrag af[4];
        #pragma unroll
        for (int ds=0;ds<4;++ds) af[ds] = *(const hfrag*)&W16[(Ri*4+ds)*512 + lane*8];
        #pragma unroll
        for (int jj=0;jj<2;++jj){
          ffrag acc = (ffrag){0.f,0.f,0.f,0.f};
          #pragma unroll
          for (int ds=0;ds<4;++ds) acc = MFMA16(af[ds], bf[jj][ds], acc);
          const int src = (wj*2+jj)*16 + l15;
          const int sds = src>>5, s16 = 16*((src>>3)&3), s7 = src&7;
          #pragma unroll
          for (int r=0;r<4;++r)
            m16[((Ri*4 + sds)*64 + 4*g + r + s16)*8 + s7] = (_Float16)acc[r];
        }
      }
    }
    __syncthreads();

    // GEMM2: D2[dst][dout] = sum_src A_hat[dst][src] m[src][dout]; +bg, tanh
    {
      hfrag bf[2][4];
      float bgv[2];
      #pragma unroll
      for (int jj=0;jj<2;++jj){
        const int jg = wj*2+jj;
        #pragma unroll
        for (int ds=0;ds<4;++ds) bf[jj][ds] = *(const hfrag*)&m16[(jg*4+ds)*512 + lane*8];
        bgv[jj] = bg[l*DD + jg*16 + l15];
      }
      #pragma unroll
      for (int it=0;it<4;++it){
        const int Ri = wi*4+it;
        hfrag af[4];
        #pragma unroll
        for (int ds=0;ds<4;++ds) af[ds] = *(const hfrag*)&A16[(Ri*4+ds)*512 + lane*8];
        #pragma unroll
        for (int jj=0;jj<2;++jj){
          ffrag acc = (ffrag){0.f,0.f,0.f,0.f};
          #pragma unroll
          for (int ds=0;ds<4;++ds) acc = MFMA16(af[ds], bf[jj][ds], acc);
          const int dout = (wj*2+jj)*16 + l15;
          if (l < 3){
            const int dds = dout>>5, d16 = 16*((dout>>3)&3), d7 = dout&7;
            #pragma unroll
            for (int r=0;r<4;++r){
              float v = tanh_fast(acc[r] + bgv[jj]);
              h16[((Ri*4 + dds)*64 + 4*g + r + d16)*8 + d7] = (_Float16)v;
            }
          } else {
            #pragma unroll
            for (int r=0;r<4;++r){
              float v = tanh_fast(acc[r] + bgv[jj]);
              out[((size_t)b*128 + Ri*16 + 4*g + r)*(2*DD) + dout] = v;
            }
          }
        }
      }
    }
    __syncthreads();
  }
}

// merged Q/K/V projections -> f16, one launch, grid 768.
// mode 0 (Q): q16[row][d] plain; mode 1 (K): fidx frag-order; mode 2 (V): kappa V^T
__global__ __launch_bounds__(256) void k_proj3(const float* __restrict__ A,
                                               const float* __restrict__ Wq, const float* __restrict__ bq_,
                                               const float* __restrict__ Wk, const float* __restrict__ bk_,
                                               const float* __restrict__ Wv, const float* __restrict__ bv_,
                                               _Float16* __restrict__ q16,
                                               _Float16* __restrict__ k16,
                                               _Float16* __restrict__ vT) {
  __shared__ float As[32*132];
  __shared__ float Ws[128*132];
  const int mode = blockIdx.x >> 8;
  const int row0 = (blockIdx.x & 255) * 32;
  const float* W    = (mode==0) ? Wq : (mode==1) ? Wk : Wv;
  const float* bias = (mode==0) ? bq_ : (mode==1) ? bk_ : bv_;
  int tid = threadIdx.x;
  #pragma unroll
  for (int i=0;i<4;i++){
    int idx = i*256+tid;
    int r = idx>>5, c4 = (idx&31)<<2;
    *(float4*)&As[r*132+c4] = *(const float4*)&A[(row0+r)*DD + c4];
  }
  #pragma unroll
  for (int i=0;i<16;i++){
    int idx = i*256+tid;
    int r = idx>>5, c4 = (idx&31)<<2;
    *(float4*)&Ws[r*132+c4] = *(const float4*)&W[r*DD + c4];
  }
  __syncthreads();
  int rg = tid>>4, cg = tid&15;
  int r0 = rg*2, c0 = cg*8;
  float acc[2][8];
  #pragma unroll
  for (int a=0;a<2;a++)
    #pragma unroll
    for (int b=0;b<8;b++) acc[a][b]=0.f;
  for (int kk=0;kk<128;kk+=4){
    float a0[4], a1[4];
    *(float4*)a0 = *(float4*)&As[r0*132+kk];
    *(float4*)a1 = *(float4*)&As[(r0+1)*132+kk];
    #pragma unroll
    for (int j=0;j<4;j++){
      float w[8];
      *(float4*)&w[0] = *(float4*)&Ws[(kk+j)*132+c0];
      *(float4*)&w[4] = *(float4*)&Ws[(kk+j)*132+c0+4];
      #pragma unroll
      for (int m=0;m<8;m++){
        acc[0][m] += a0[j]*w[m];
        acc[1][m] += a1[j]*w[m];
      }
    }
  }
  #pragma unroll
  for (int a=0;a<2;a++){
    int row = row0 + r0 + a;
    float val[8];
    #pragma unroll
    for (int m=0;m<8;m++) val[m] = acc[a][m] + bias[c0+m];
    if (mode == 0) {
      hfrag t;
      #pragma unroll
      for (int m=0;m<8;m++) t[m] = (_Float16)val[m];
      *(hfrag*)&q16[(size_t)row*DD + c0] = t;
    } else if (mode == 1) {
      hfrag t;
      #pragma unroll
      for (int m=0;m<8;m++) t[m] = (_Float16)val[m];
      int R = row>>4, l15r = row&15, dsx = cg>>2, gx = cg&3;
      *(hfrag*)&k16[((size_t)(R*4+dsx)*64 + l15r + 16*gx)*8] = t;
    } else {
      int C = row>>5, kloc = row&31;
      int gx = (kloc&15)>>2;
      int jx = ((kloc>>4)<<2) | (kloc&3);
      #pragma unroll
      for (int m=0;m<8;m++){
        int d = c0+m;
        vT[((size_t)(C*8 + (d>>4))*64 + (d&15) + 16*gx)*8 + jx] = (_Float16)val[m];
      }
    }
  }
}

// W2 = Wo @ (Wc[:128]+Wc[128:]);  b2 = bo @ (Wc[:128]+Wc[128:]) + bc
__global__ __launch_bounds__(256) void k_w2(const float* __restrict__ Wo, const float* __restrict__ bo,
                                            const float* __restrict__ Wc, const float* __restrict__ bc,
                                            float* __restrict__ W2, float* __restrict__ b2) {
  if (blockIdx.x < 64) {
    int gid = blockIdx.x*256 + threadIdx.x;
    int i = gid>>7, j = gid&127;
    float s = 0.f;
    for (int k2=0;k2<128;k2++)
      s += Wo[i*DD+k2]*(Wc[k2*DD+j] + Wc[(k2+128)*DD+j]);
    W2[i*DD+j] = s;
  } else if (threadIdx.x < 128) {
    int j = threadIdx.x;
    float s = bc[j];
    for (int k2=0;k2<128;k2++)
      s += bo[k2]*(Wc[k2*DD+j] + Wc[(k2+128)*DD+j]);
    b2[j] = s;
  }
}

// 8-warp independent-softmax MFMA flash attention (unchanged from round 6).
__global__ __launch_bounds__(512,2) void k_flash4(
    const _Float16* __restrict__ q16, const _Float16* __restrict__ k16f,
    const _Float16* __restrict__ vTf,
    _Float16* __restrict__ Opart, float* __restrict__ pm, float* __restrict__ pl)
{
  __shared__ _Float16 Kb[2][8192];
  __shared__ _Float16 Vb[2][8192];
  const int tid  = threadIdx.x;
  const int lane = tid & 63;
  const int w8   = tid >> 6;
  const int l15  = lane & 15;
  const int g    = lane >> 4;
  const int qt   = blockIdx.x >> 3;
  const int sp   = blockIdx.x & 7;
  const int q0   = qt*256 + w8*32;

  hfrag qf[2][4];
  #pragma unroll
  for (int qb=0;qb<2;++qb)
    #pragma unroll
    for (int ds=0;ds<4;++ds)
      qf[qb][ds] = *(const hfrag*)&q16[(size_t)(q0+16*qb+l15)*DD + 32*ds + 8*g];

  float mrun[2] = {-1e30f,-1e30f}, lrun[2] = {0.f,0.f};
  ffrag o[2][8];
  #pragma unroll
  for (int qb=0;qb<2;++qb)
    #pragma unroll
    for (int nt=0;nt<8;++nt) o[qb][nt] = (ffrag){0.f,0.f,0.f,0.f};

  const size_t kbase = (size_t)(sp*1024)*DD;
  {
    const _Float16* Ks = k16f + kbase;
    const _Float16* Vs = vTf  + kbase;
    #pragma unroll
    for (int j=0;j<2;++j){
      const int c = w8*2 + j;
      GLOAD16(Ks + c*512 + lane*8, &Kb[0][c*512]);
      GLOAD16(Vs + c*512 + lane*8, &Vb[0][c*512]);
    }
  }
  __syncthreads();

  int cur = 0;
  for (int t=0; t<16; ++t){
    if (t < 15){
      const _Float16* Ks = k16f + kbase + (size_t)(t+1)*64*DD;
      const _Float16* Vs = vTf  + kbase + (size_t)(t+1)*64*DD;
      #pragma unroll
      for (int j=0;j<2;++j){
        const int c = w8*2 + j;
        GLOAD16(Ks + c*512 + lane*8, &Kb[cur^1][c*512]);
        GLOAD16(Vs + c*512 + lane*8, &Vb[cur^1][c*512]);
      }
    }

    ffrag s2[2][4];
    #pragma unroll
    for (int qb=0;qb<2;++qb)
      #pragma unroll
      for (int mt=0;mt<4;++mt) s2[qb][mt] = (ffrag){0.f,0.f,0.f,0.f};
    __builtin_amdgcn_s_setprio(1);
    #pragma unroll
    for (int mt=0;mt<4;++mt)
      #pragma unroll
      for (int ds=0;ds<4;++ds){
        hfrag kf = *(const hfrag*)&Kb[cur][(mt*4+ds)*512 + lane*8];
        s2[0][mt] = MFMA16(kf, qf[0][ds], s2[0][mt]);
        s2[1][mt] = MFMA16(kf, qf[1][ds], s2[1][mt]);
      }
    __builtin_amdgcn_s_setprio(0);

    #pragma unroll
    for (int qb=0;qb<2;++qb){
      float tmax = -1e30f;
      #pragma unroll
      for (int mt=0;mt<4;++mt)
        tmax = fmaxf(tmax, fmaxf(fmaxf(s2[qb][mt][0], s2[qb][mt][1]),
                                 fmaxf(s2[qb][mt][2], s2[qb][mt][3])));
      tmax = fmaxf(tmax, __shfl_xor(tmax,16));
      tmax = fmaxf(tmax, __shfl_xor(tmax,32));
      const float mnew = fmaxf(mrun[qb], tmax);
      float psum = 0.f;
      #pragma unroll
      for (int mt=0;mt<4;++mt)
        #pragma unroll
        for (int r=0;r<4;++r){ float e = __expf(s2[qb][mt][r]-mnew); s2[qb][mt][r]=e; psum += e; }
      psum += __shfl_xor(psum,16);
      psum += __shfl_xor(psum,32);
      if (__any(mnew > mrun[qb])){
        const float sc = __expf(mrun[qb]-mnew);
        lrun[qb] = lrun[qb]*sc + psum;
        mrun[qb] = mnew;
        #pragma unroll
        for (int r=0;r<4;++r){
          const float scr = __shfl(sc, 4*g+r);
          #pragma unroll
          for (int nt=0;nt<8;++nt) o[qb][nt][r] *= scr;
        }
      } else {
        lrun[qb] += psum;
      }
    }

    __builtin_amdgcn_s_setprio(1);
    #pragma unroll
    for (int c2=0;c2<2;++c2){
      hfrag pf0, pf1;
      #pragma unroll
      for (int j=0;j<8;++j){
        pf0[j] = (_Float16)s2[0][2*c2+(j>>2)][j&3];
        pf1[j] = (_Float16)s2[1][2*c2+(j>>2)][j&3];
      }
      #pragma unroll
      for (int nt=0;nt<8;++nt){
        hfrag vf = *(const hfrag*)&Vb[cur][(c2*8+nt)*512 + lane*8];
        o[0][nt] = MFMA16(pf0, vf, o[0][nt]);
        o[1][nt] = MFMA16(pf1, vf, o[1][nt]);
      }
    }
    __builtin_amdgcn_s_setprio(0);

    __syncthreads();
    cur ^= 1;
  }

  #pragma unroll
  for (int qb=0;qb<2;++qb){
    #pragma unroll
    for (int r=0;r<4;++r){
      _Float16* dst = &Opart[((size_t)sp*TT + q0 + 16*qb + 4*g + r)*DD];
      #pragma unroll
      for (int nt=0;nt<8;++nt)
        dst[16*nt + l15] = (_Float16)o[qb][nt][r];
    }
    if (g==0){
      pm[(size_t)sp*TT + q0 + 16*qb + l15] = mrun[qb];
      pl[(size_t)sp*TT + q0 + 16*qb + l15] = lrun[qb];
    }
  }
}

// final GEMM with inline 8-split softmax combine on the A-load
__global__ __launch_bounds__(256) void k_gemm_final(const _Float16* __restrict__ Opart,
                                                    const float* __restrict__ pm, const float* __restrict__ pl,
                                                    const float* __restrict__ W2, const float* __restrict__ b2,
                                                    float* __restrict__ out) {
  __shared__ float As[32*132];
  __shared__ float Ws[128*132];
  int tid = threadIdx.x;
  int row0 = blockIdx.x*32;
  #pragma unroll
  for (int i=0;i<4;i++){
    int idx = i*256+tid;
    int r = idx>>5, c4 = (idx&31)<<2;
    int t = row0 + r;
    float ms[8], ls[8];
    #pragma unroll
    for (int s=0;s<8;++s){ ms[s]=pm[(size_t)s*TT+t]; ls[s]=pl[(size_t)s*TT+t]; }
    float mx = ms[0];
    #pragma unroll
    for (int s=1;s<8;++s) mx = fmaxf(mx, ms[s]);
    float es[8]; float den = 0.f;
    #pragma unroll
    for (int s=0;s<8;++s){ es[s]=__expf(ms[s]-mx); den += ls[s]*es[s]; }
    float4 vv = {0.f,0.f,0.f,0.f};
    #pragma unroll
    for (int s=0;s<8;++s){
      float us = es[s]/den;
      h4 a = *(const h4*)&Opart[((size_t)s*TT + t)*DD + c4];
      vv.x += us*(float)a[0]; vv.y += us*(float)a[1];
      vv.z += us*(float)a[2]; vv.w += us*(float)a[3];
    }
    *(float4*)&As[r*132+c4] = vv;
  }
  #pragma unroll
  for (int i=0;i<16;i++){
    int idx = i*256+tid;
    int r = idx>>5, c4 = (idx&31)<<2;
    *(float4*)&Ws[r*132+c4] = *(const float4*)&W2[r*DD + c4];
  }
  __syncthreads();
  int rg = tid>>4, cg = tid&15;
  int r0 = rg*2, c0 = cg*8;
  float acc[2][8];
  #pragma unroll
  for (int a=0;a<2;a++)
    #pragma unroll
    for (int b=0;b<8;b++) acc[a][b]=0.f;
  for (int kk=0;kk<128;kk+=4){
    float a0[4], a1[4];
    *(float4*)a0 = *(float4*)&As[r0*132+kk];
    *(float4*)a1 = *(float4*)&As[(r0+1)*132+kk];
    #pragma unroll
    for (int j=0;j<4;j++){
      float w[8];
      *(float4*)&w[0] = *(float4*)&Ws[(kk+j)*132+c0];
      *(float4*)&w[4] = *(float4*)&Ws[(kk+j)*132+c0+4];
      #pragma unroll
      for (int m=0;m<8;m++){
        acc[0][m] += a0[j]*w[m];
        acc[1][m] += a1[j]*w[m];
      }
    }
  }
  #pragma unroll
  for (int a=0;a<2;a++){
    float outv[8];
    #pragma unroll
    for (int m=0;m<8;m++) outv[m] = acc[a][m] + b2[c0+m];
    float* dst = &out[(size_t)(row0+r0+a)*(2*DD) + DD + c0];
    *(float4*)&dst[0] = *(float4*)&outv[0];
    *(float4*)&dst[4] = *(float4*)&outv[4];
  }
}

extern "C" void kernel_launch(void* const* d_in, const int* in_sizes, int n_in,
                              void* d_out, int out_size, void* d_ws, size_t ws_size,
                              hipStream_t stream) {
  const float* x  = (const float*)d_in[0];
  const int* edges = (const int*)d_in[1];
  const float* Wg = (const float*)d_in[2];
  const float* bg = (const float*)d_in[3];
  const float* Wq = (const float*)d_in[4];
  const float* bq = (const float*)d_in[5];
  const float* Wk = (const float*)d_in[6];
  const float* bk = (const float*)d_in[7];
  const float* Wv = (const float*)d_in[8];
  const float* bv = (const float*)d_in[9];
  const float* Wo = (const float*)d_in[10];
  const float* bo = (const float*)d_in[11];
  const float* Wc = (const float*)d_in[12];
  const float* bc = (const float*)d_in[13];
  float* out = (float*)d_out;
  char* ws = (char*)d_ws;

  float* W2  = (float*)(ws + WS_W2);
  float* b2  = (float*)(ws + WS_B2);
  float* pm  = (float*)(ws + WS_PM);
  float* pl  = (float*)(ws + WS_PL);
  _Float16* Opart = (_Float16*)(ws + WS_OPART);
  _Float16* q16 = (_Float16*)(ws + WS_Q16);
  _Float16* k16 = (_Float16*)(ws + WS_K16);
  _Float16* vT  = (_Float16*)(ws + WS_VT);

  // fused CSR + 4-layer GCN (one block per graph) -> out[:, :128]
  k_gcn<<<64,512,0,stream>>>(x, edges, Wg, bg, out);

  // attention path
  k_proj3<<<768,256,0,stream>>>(x, Wq, bq, Wk, bk, Wv, bv, q16, k16, vT);
  k_w2<<<65,256,0,stream>>>(Wo, bo, Wc, bc, W2, b2);
  k_flash4<<<256,512,0,stream>>>(q16, k16, vT, Opart, pm, pl);
  k_gemm_final<<<256,256,0,stream>>>(Opart, pm, pl, W2, b2, out);
}

// Round 8
// 109.290 us; speedup vs baseline: 2.5624x; 1.2493x over previous
//
#include <hip/hip_runtime.h>
#include <math.h>

#define TT 8192
#define DD 128
#define GB 64
#define GN 128
#define GE 2048

// ---- workspace layout (bytes) ----
#define WS_W2      (644u<<10)    // 128*128 f32
#define WS_B2      (708u<<10)    // 128 f32
#define WS_Q16     (1u<<20)      // 2MB f16
#define WS_K16     (3u<<20)      // 2MB f16 frag-order
#define WS_VT      (5u<<20)      // 2MB f16 frag-order (kappa)
#define WS_OPART   (7u<<20)      // 16MB: 8 x 8192 x 128 f16 partials
#define WS_PM      (23u<<20)     // 8*8192 f32 (256K)
#define WS_PL      ((23u<<20)+(256u<<10))

typedef _Float16 hfrag  __attribute__((ext_vector_type(8)));
typedef _Float16 h4     __attribute__((ext_vector_type(4)));
typedef float    ffrag  __attribute__((ext_vector_type(4)));

#define MFMA16(a,b,c) __builtin_amdgcn_mfma_f32_16x16x32_f16((a),(b),(c),0,0,0)

typedef __attribute__((address_space(1))) unsigned int gu32_t;
typedef __attribute__((address_space(3))) unsigned int lu32_t;
#define GLOAD16(gp, lp) __builtin_amdgcn_global_load_lds((gu32_t*)(const void*)(gp), (lu32_t*)(void*)(lp), 16, 0, 0)

// fragment-order element index (proven): A-frag = fidx(i,k); B-frag = fidx(j,k)
__device__ __forceinline__ int fidx(int r_, int c_) {
  return (((r_>>4)*4 + (c_>>5))*64 + (r_&15) + 16*((c_>>3)&3))*8 + (c_&7);
}

__device__ __forceinline__ float tanh_fast(float x) {
  float e = __expf(2.f*x);
  return 1.f - 2.f/(e+1.f);
}

// =====================================================================
// fused_pre: one launch, 260 blocks x 512 threads, block-role dispatch.
//   blocks   0..63 : per-graph fused GCN (CSR densify + 4 MFMA layers) -> out[:, :128]
//   blocks  64..255: Q/K/V projections (fp32, 128 rows/block) -> q16/k16/vT (f16 layouts)
//   blocks 256..259: W2 = Wo@(Wc_top+Wc_bot) rows + b2
// GCN and projections are independent; roles run concurrently (1 block/CU, 132KB LDS).
// =====================================================================
__global__ __launch_bounds__(512,1) void fused_pre(
    const float* __restrict__ x, const int* __restrict__ edges,
    const float* __restrict__ Wg, const float* __restrict__ bg,
    const float* __restrict__ Wq, const float* __restrict__ bq_,
    const float* __restrict__ Wk, const float* __restrict__ bk_,
    const float* __restrict__ Wv, const float* __restrict__ bv_,
    const float* __restrict__ Wo, const float* __restrict__ bo,
    const float* __restrict__ Wc, const float* __restrict__ bc,
    _Float16* __restrict__ q16, _Float16* __restrict__ k16, _Float16* __restrict__ vT,
    float* __restrict__ W2, float* __restrict__ b2,
    float* __restrict__ out)
{
  __shared__ __align__(16) char Lm[135168];
  const int tid  = threadIdx.x;
  const int bid  = blockIdx.x;

  if (bid < 64) {
    // ---------------- GCN role (verbatim from round-7 k_gcn) ----------------
    float*    Af  = (float*)Lm;
    _Float16* W16 = (_Float16*)Lm;
    _Float16* m16 = (_Float16*)(Lm + 32768);
    _Float16* h16 = (_Float16*)(Lm + 65536);
    _Float16* A16 = (_Float16*)(Lm + 98304);
    int*      cnt = (int*)(Lm + 131072);
    float*    nrm = (float*)(Lm + 131584);

    const int lane = tid & 63;
    const int w8   = tid >> 6;
    const int l15  = lane & 15;
    const int g    = lane >> 4;
    const int wi   = w8 >> 2;
    const int wj   = w8 & 3;
    const int b    = bid;
    const int* eg  = edges + b*2*GE;

    #pragma unroll
    for (int i=0;i<8;++i) ((float4*)Af)[i*512 + tid] = (float4){0.f,0.f,0.f,0.f};
    if (tid < 128) cnt[tid] = 0;
    __syncthreads();
    #pragma unroll
    for (int i=0;i<4;++i) atomicAdd(&cnt[eg[GE + i*512 + tid]], 1);
    __syncthreads();
    if (tid < 128) nrm[tid] = rsqrtf(1.f + (float)cnt[tid]);
    __syncthreads();
    #pragma unroll
    for (int i=0;i<4;++i){
      int s = eg[i*512 + tid], d = eg[GE + i*512 + tid];
      atomicAdd(&Af[d*128 + s], nrm[s]*nrm[d]);
    }
    __syncthreads();
    if (tid < 128) Af[tid*128 + tid] += nrm[tid]*nrm[tid];
    __syncthreads();
    #pragma unroll
    for (int i=0;i<8;++i){
      int i4 = i*512 + tid;
      float4 v = ((const float4*)Af)[i4];
      int dst = i4>>5, s4 = (i4&31)<<2;
      h4 t; t[0]=(_Float16)v.x; t[1]=(_Float16)v.y; t[2]=(_Float16)v.z; t[3]=(_Float16)v.w;
      *(h4*)&A16[fidx(dst, s4)] = t;
    }
    #pragma unroll
    for (int i=0;i<8;++i){
      int i4 = i*512 + tid;
      int n = i4>>5, k4 = (i4&31)<<2;
      float4 v = *(const float4*)&x[((size_t)b*128 + n)*128 + k4];
      h4 t; t[0]=(_Float16)v.x; t[1]=(_Float16)v.y; t[2]=(_Float16)v.z; t[3]=(_Float16)v.w;
      *(h4*)&h16[fidx(n, k4)] = t;
    }
    __syncthreads();

    for (int l=0; l<4; ++l){
      const float* Wl = Wg + l*DD*DD;
      #pragma unroll
      for (int i=0;i<8;++i){
        int i4 = i*512 + tid;
        int k = i4>>5, i0 = (i4&31)<<2;
        float4 v = *(const float4*)&Wl[k*DD + i0];
        W16[fidx(i0+0,k)] = (_Float16)v.x;
        W16[fidx(i0+1,k)] = (_Float16)v.y;
        W16[fidx(i0+2,k)] = (_Float16)v.z;
        W16[fidx(i0+3,k)] = (_Float16)v.w;
      }
      __syncthreads();

      {
        hfrag bf[2][4];
        #pragma unroll
        for (int jj=0;jj<2;++jj){
          const int jg = wj*2+jj;
          #pragma unroll
          for (int ds=0;ds<4;++ds) bf[jj][ds] = *(const hfrag*)&h16[(jg*4+ds)*512 + lane*8];
        }
        #pragma unroll
        for (int it=0;it<4;++it){
          const int Ri = wi*4+it;
          hfrag af[4];
          #pragma unroll
          for (int ds=0;ds<4;++ds) af[ds] = *(const hfrag*)&W16[(Ri*4+ds)*512 + lane*8];
          #pragma unroll
          for (int jj=0;jj<2;++jj){
            ffrag acc = (ffrag){0.f,0.f,0.f,0.f};
            #pragma unroll
            for (int ds=0;ds<4;++ds) acc = MFMA16(af[ds], bf[jj][ds], acc);
            const int src = (wj*2+jj)*16 + l15;
            const int sds = src>>5, s16 = 16*((src>>3)&3), s7 = src&7;
            #pragma unroll
            for (int r=0;r<4;++r)
              m16[((Ri*4 + sds)*64 + 4*g + r + s16)*8 + s7] = (_Float16)acc[r];
          }
        }
      }
      __syncthreads();

      {
        hfrag bf[2][4];
        float bgv[2];
        #pragma unroll
        for (int jj=0;jj<2;++jj){
          const int jg = wj*2+jj;
          #pragma unroll
          for (int ds=0;ds<4;++ds) bf[jj][ds] = *(const hfrag*)&m16[(jg*4+ds)*512 + lane*8];
          bgv[jj] = bg[l*DD + jg*16 + l15];
        }
        #pragma unroll
        for (int it=0;it<4;++it){
          const int Ri = wi*4+it;
          hfrag af[4];
          #pragma unroll
          for (int ds=0;ds<4;++ds) af[ds] = *(const hfrag*)&A16[(Ri*4+ds)*512 + lane*8];
          #pragma unroll
          for (int jj=0;jj<2;++jj){
            ffrag acc = (ffrag){0.f,0.f,0.f,0.f};
            #pragma unroll
            for (int ds=0;ds<4;++ds) acc = MFMA16(af[ds], bf[jj][ds], acc);
            const int dout = (wj*2+jj)*16 + l15;
            if (l < 3){
              const int dds = dout>>5, d16 = 16*((dout>>3)&3), d7 = dout&7;
              #pragma unroll
              for (int r=0;r<4;++r){
                float v = tanh_fast(acc[r] + bgv[jj]);
                h16[((Ri*4 + dds)*64 + 4*g + r + d16)*8 + d7] = (_Float16)v;
              }
            } else {
              #pragma unroll
              for (int r=0;r<4;++r){
                float v = tanh_fast(acc[r] + bgv[jj]);
                out[((size_t)b*128 + Ri*16 + 4*g + r)*(2*DD) + dout] = v;
              }
            }
          }
        }
      }
      __syncthreads();
    }
  } else if (bid < 256) {
    // ---------------- projection role (fp32 math == old k_proj3) ----------------
    const int idx  = bid - 64;         // 0..191
    const int mode = idx >> 6;         // 0:Q 1:K 2:V
    const int row0 = (idx & 63) * 128; // 128 rows per block
    const float* W    = (mode==0) ? Wq : (mode==1) ? Wk : Wv;
    const float* bias = (mode==0) ? bq_ : (mode==1) ? bk_ : bv_;
    float* Xs  = (float*)Lm;           // [128][132]
    float* Ws2 = (float*)(Lm + 67584); // [128][132]

    #pragma unroll
    for (int i=0;i<8;++i){
      int i2 = i*512 + tid;
      int r = i2>>5, c4 = (i2&31)<<2;
      *(float4*)&Ws2[r*132+c4] = *(const float4*)&W[r*DD + c4];
      *(float4*)&Xs [r*132+c4] = *(const float4*)&x[(size_t)(row0+r)*DD + c4];
    }
    __syncthreads();

    const int r0 = (tid>>4)*4;       // 4 rows per thread
    const int cg = tid&15;
    const int c0 = cg*8;
    float acc[4][8];
    #pragma unroll
    for (int t=0;t<4;++t)
      #pragma unroll
      for (int m=0;m<8;++m) acc[t][m]=0.f;
    for (int kk=0;kk<128;kk+=4){
      float a[4][4];
      #pragma unroll
      for (int t=0;t<4;++t) *(float4*)a[t] = *(float4*)&Xs[(r0+t)*132+kk];
      #pragma unroll
      for (int j=0;j<4;++j){
        float w[8];
        *(float4*)&w[0] = *(float4*)&Ws2[(kk+j)*132+c0];
        *(float4*)&w[4] = *(float4*)&Ws2[(kk+j)*132+c0+4];
        #pragma unroll
        for (int t=0;t<4;++t)
          #pragma unroll
          for (int m=0;m<8;++m) acc[t][m] += a[t][j]*w[m];
      }
    }
    #pragma unroll
    for (int t=0;t<4;++t){
      const int row = row0 + r0 + t;
      float val[8];
      #pragma unroll
      for (int m=0;m<8;++m) val[m] = acc[t][m] + bias[c0+m];
      if (mode == 0) {
        hfrag h;
        #pragma unroll
        for (int m=0;m<8;++m) h[m] = (_Float16)val[m];
        *(hfrag*)&q16[(size_t)row*DD + c0] = h;
      } else if (mode == 1) {
        hfrag h;
        #pragma unroll
        for (int m=0;m<8;++m) h[m] = (_Float16)val[m];
        int R = row>>4, l15r = row&15, dsx = cg>>2, gx = cg&3;
        *(hfrag*)&k16[((size_t)(R*4+dsx)*64 + l15r + 16*gx)*8] = h;
      } else {
        int C = row>>5, kloc = row&31;
        int gx = (kloc&15)>>2;
        int jx = ((kloc>>4)<<2) | (kloc&3);
        #pragma unroll
        for (int m=0;m<8;++m){
          int d = c0+m;
          vT[((size_t)(C*8 + (d>>4))*64 + (d&15) + 16*gx)*8 + jx] = (_Float16)val[m];
        }
      }
    }
  } else {
    // ---------------- W2/b2 role ----------------
    const int widx = bid - 256;        // 0..3 -> rows [widx*32, +32)
    float* Wcs = (float*)Lm;           // [128][128] f32 (Wc_top + Wc_bot)
    #pragma unroll
    for (int i=0;i<32;++i){
      int i2 = i*512 + tid;
      Wcs[i2] = Wc[i2] + Wc[i2 + 16384];
    }
    __syncthreads();
    const int r  = tid>>4;             // 0..31
    const int c0 = (tid&15)*8;
    const int ig = widx*32 + r;
    float acc[8];
    #pragma unroll
    for (int m=0;m<8;++m) acc[m]=0.f;
    for (int k=0;k<128;++k){
      float wo = Wo[ig*DD + k];
      #pragma unroll
      for (int m=0;m<8;++m) acc[m] += wo*Wcs[k*128 + c0 + m];
    }
    #pragma unroll
    for (int m=0;m<8;++m) W2[ig*DD + c0 + m] = acc[m];
    if (widx == 0){
      __syncthreads();
      if (tid < 128){
        float s = bc[tid];
        for (int k=0;k<128;++k) s += bo[k]*Wcs[k*128 + tid];
        b2[tid] = s;
      }
    }
  }
}

// 8-warp independent-softmax MFMA flash attention (unchanged, proven).
__global__ __launch_bounds__(512,2) void k_flash4(
    const _Float16* __restrict__ q16, const _Float16* __restrict__ k16f,
    const _Float16* __restrict__ vTf,
    _Float16* __restrict__ Opart, float* __restrict__ pm, float* __restrict__ pl)
{
  __shared__ _Float16 Kb[2][8192];
  __shared__ _Float16 Vb[2][8192];
  const int tid  = threadIdx.x;
  const int lane = tid & 63;
  const int w8   = tid >> 6;
  const int l15  = lane & 15;
  const int g    = lane >> 4;
  const int qt   = blockIdx.x >> 3;
  const int sp   = blockIdx.x & 7;
  const int q0   = qt*256 + w8*32;

  hfrag qf[2][4];
  #pragma unroll
  for (int qb=0;qb<2;++qb)
    #pragma unroll
    for (int ds=0;ds<4;++ds)
      qf[qb][ds] = *(const hfrag*)&q16[(size_t)(q0+16*qb+l15)*DD + 32*ds + 8*g];

  float mrun[2] = {-1e30f,-1e30f}, lrun[2] = {0.f,0.f};
  ffrag o[2][8];
  #pragma unroll
  for (int qb=0;qb<2;++qb)
    #pragma unroll
    for (int nt=0;nt<8;++nt) o[qb][nt] = (ffrag){0.f,0.f,0.f,0.f};

  const size_t kbase = (size_t)(sp*1024)*DD;
  {
    const _Float16* Ks = k16f + kbase;
    const _Float16* Vs = vTf  + kbase;
    #pragma unroll
    for (int j=0;j<2;++j){
      const int c = w8*2 + j;
      GLOAD16(Ks + c*512 + lane*8, &Kb[0][c*512]);
      GLOAD16(Vs + c*512 + lane*8, &Vb[0][c*512]);
    }
  }
  __syncthreads();

  int cur = 0;
  for (int t=0; t<16; ++t){
    if (t < 15){
      const _Float16* Ks = k16f + kbase + (size_t)(t+1)*64*DD;
      const _Float16* Vs = vTf  + kbase + (size_t)(t+1)*64*DD;
      #pragma unroll
      for (int j=0;j<2;++j){
        const int c = w8*2 + j;
        GLOAD16(Ks + c*512 + lane*8, &Kb[cur^1][c*512]);
        GLOAD16(Vs + c*512 + lane*8, &Vb[cur^1][c*512]);
      }
    }

    ffrag s2[2][4];
    #pragma unroll
    for (int qb=0;qb<2;++qb)
      #pragma unroll
      for (int mt=0;mt<4;++mt) s2[qb][mt] = (ffrag){0.f,0.f,0.f,0.f};
    __builtin_amdgcn_s_setprio(1);
    #pragma unroll
    for (int mt=0;mt<4;++mt)
      #pragma unroll
      for (int ds=0;ds<4;++ds){
        hfrag kf = *(const hfrag*)&Kb[cur][(mt*4+ds)*512 + lane*8];
        s2[0][mt] = MFMA16(kf, qf[0][ds], s2[0][mt]);
        s2[1][mt] = MFMA16(kf, qf[1][ds], s2[1][mt]);
      }
    __builtin_amdgcn_s_setprio(0);

    #pragma unroll
    for (int qb=0;qb<2;++qb){
      float tmax = -1e30f;
      #pragma unroll
      for (int mt=0;mt<4;++mt)
        tmax = fmaxf(tmax, fmaxf(fmaxf(s2[qb][mt][0], s2[qb][mt][1]),
                                 fmaxf(s2[qb][mt][2], s2[qb][mt][3])));
      tmax = fmaxf(tmax, __shfl_xor(tmax,16));
      tmax = fmaxf(tmax, __shfl_xor(tmax,32));
      const float mnew = fmaxf(mrun[qb], tmax);
      float psum = 0.f;
      #pragma unroll
      for (int mt=0;mt<4;++mt)
        #pragma unroll
        for (int r=0;r<4;++r){ float e = __expf(s2[qb][mt][r]-mnew); s2[qb][mt][r]=e; psum += e; }
      psum += __shfl_xor(psum,16);
      psum += __shfl_xor(psum,32);
      if (__any(mnew > mrun[qb])){
        const float sc = __expf(mrun[qb]-mnew);
        lrun[qb] = lrun[qb]*sc + psum;
        mrun[qb] = mnew;
        #pragma unroll
        for (int r=0;r<4;++r){
          const float scr = __shfl(sc, 4*g+r);
          #pragma unroll
          for (int nt=0;nt<8;++nt) o[qb][nt][r] *= scr;
        }
      } else {
        lrun[qb] += psum;
      }
    }

    __builtin_amdgcn_s_setprio(1);
    #pragma unroll
    for (int c2=0;c2<2;++c2){
      hfrag pf0, pf1;
      #pragma unroll
      for (int j=0;j<8;++j){
        pf0[j] = (_Float16)s2[0][2*c2+(j>>2)][j&3];
        pf1[j] = (_Float16)s2[1][2*c2+(j>>2)][j&3];
      }
      #pragma unroll
      for (int nt=0;nt<8;++nt){
        hfrag vf = *(const hfrag*)&Vb[cur][(c2*8+nt)*512 + lane*8];
        o[0][nt] = MFMA16(pf0, vf, o[0][nt]);
        o[1][nt] = MFMA16(pf1, vf, o[1][nt]);
      }
    }
    __builtin_amdgcn_s_setprio(0);

    __syncthreads();
    cur ^= 1;
  }

  #pragma unroll
  for (int qb=0;qb<2;++qb){
    #pragma unroll
    for (int r=0;r<4;++r){
      _Float16* dst = &Opart[((size_t)sp*TT + q0 + 16*qb + 4*g + r)*DD];
      #pragma unroll
      for (int nt=0;nt<8;++nt)
        dst[16*nt + l15] = (_Float16)o[qb][nt][r];
    }
    if (g==0){
      pm[(size_t)sp*TT + q0 + 16*qb + l15] = mrun[qb];
      pl[(size_t)sp*TT + q0 + 16*qb + l15] = lrun[qb];
    }
  }
}

// final GEMM with inline 8-split softmax combine on the A-load (unchanged)
__global__ __launch_bounds__(256) void k_gemm_final(const _Float16* __restrict__ Opart,
                                                    const float* __restrict__ pm, const float* __restrict__ pl,
                                                    const float* __restrict__ W2, const float* __restrict__ b2,
                                                    float* __restrict__ out) {
  __shared__ float As[32*132];
  __shared__ float Ws[128*132];
  int tid = threadIdx.x;
  int row0 = blockIdx.x*32;
  #pragma unroll
  for (int i=0;i<4;i++){
    int idx = i*256+tid;
    int r = idx>>5, c4 = (idx&31)<<2;
    int t = row0 + r;
    float ms[8], ls[8];
    #pragma unroll
    for (int s=0;s<8;++s){ ms[s]=pm[(size_t)s*TT+t]; ls[s]=pl[(size_t)s*TT+t]; }
    float mx = ms[0];
    #pragma unroll
    for (int s=1;s<8;++s) mx = fmaxf(mx, ms[s]);
    float es[8]; float den = 0.f;
    #pragma unroll
    for (int s=0;s<8;++s){ es[s]=__expf(ms[s]-mx); den += ls[s]*es[s]; }
    float4 vv = {0.f,0.f,0.f,0.f};
    #pragma unroll
    for (int s=0;s<8;++s){
      float us = es[s]/den;
      h4 a = *(const h4*)&Opart[((size_t)s*TT + t)*DD + c4];
      vv.x += us*(float)a[0]; vv.y += us*(float)a[1];
      vv.z += us*(float)a[2]; vv.w += us*(float)a[3];
    }
    *(float4*)&As[r*132+c4] = vv;
  }
  #pragma unroll
  for (int i=0;i<16;i++){
    int idx = i*256+tid;
    int r = idx>>5, c4 = (idx&31)<<2;
    *(float4*)&Ws[r*132+c4] = *(const float4*)&W2[r*DD + c4];
  }
  __syncthreads();
  int rg = tid>>4, cg = tid&15;
  int r0 = rg*2, c0 = cg*8;
  float acc[2][8];
  #pragma unroll
  for (int a=0;a<2;a++)
    #pragma unroll
    for (int b=0;b<8;b++) acc[a][b]=0.f;
  for (int kk=0;kk<128;kk+=4){
    float a0[4], a1[4];
    *(float4*)a0 = *(float4*)&As[r0*132+kk];
    *(float4*)a1 = *(float4*)&As[(r0+1)*132+kk];
    #pragma unroll
    for (int j=0;j<4;j++){
      float w[8];
      *(float4*)&w[0] = *(float4*)&Ws[(kk+j)*132+c0];
      *(float4*)&w[4] = *(float4*)&Ws[(kk+j)*132+c0+4];
      #pragma unroll
      for (int m=0;m<8;m++){
        acc[0][m] += a0[j]*w[m];
        acc[1][m] += a1[j]*w[m];
      }
    }
  }
  #pragma unroll
  for (int a=0;a<2;a++){
    float outv[8];
    #pragma unroll
    for (int m=0;m<8;m++) outv[m] = acc[a][m] + b2[c0+m];
    float* dst = &out[(size_t)(row0+r0+a)*(2*DD) + DD + c0];
    *(float4*)&dst[0] = *(float4*)&outv[0];
    *(float4*)&dst[4] = *(float4*)&outv[4];
  }
}

extern "C" void kernel_launch(void* const* d_in, const int* in_sizes, int n_in,
                              void* d_out, int out_size, void* d_ws, size_t ws_size,
                              hipStream_t stream) {
  const float* x  = (const float*)d_in[0];
  const int* edges = (const int*)d_in[1];
  const float* Wg = (const float*)d_in[2];
  const float* bg = (const float*)d_in[3];
  const float* Wq = (const float*)d_in[4];
  const float* bq = (const float*)d_in[5];
  const float* Wk = (const float*)d_in[6];
  const float* bk = (const float*)d_in[7];
  const float* Wv = (const float*)d_in[8];
  const float* bv = (const float*)d_in[9];
  const float* Wo = (const float*)d_in[10];
  const float* bo = (const float*)d_in[11];
  const float* Wc = (const float*)d_in[12];
  const float* bc = (const float*)d_in[13];
  float* out = (float*)d_out;
  char* ws = (char*)d_ws;

  float* W2  = (float*)(ws + WS_W2);
  float* b2  = (float*)(ws + WS_B2);
  float* pm  = (float*)(ws + WS_PM);
  float* pl  = (float*)(ws + WS_PL);
  _Float16* Opart = (_Float16*)(ws + WS_OPART);
  _Float16* q16 = (_Float16*)(ws + WS_Q16);
  _Float16* k16 = (_Float16*)(ws + WS_K16);
  _Float16* vT  = (_Float16*)(ws + WS_VT);

  // GCN (64 blocks) + QKV projections (192) + W2 (4), concurrent block roles
  fused_pre<<<260,512,0,stream>>>(x, edges, Wg, bg, Wq, bq, Wk, bk, Wv, bv,
                                  Wo, bo, Wc, bc, q16, k16, vT, W2, b2, out);
  k_flash4<<<256,512,0,stream>>>(q16, k16, vT, Opart, pm, pl);
  k_gemm_final<<<256,256,0,stream>>>(Opart, pm, pl, W2, b2, out);
}